// Round 11
// baseline (858.894 us; speedup 1.0000x reference)
//
#include <hip/hip_runtime.h>
#include <math.h>

#define NN 50000
#define NE 800000
#define EMB 128
#define HID 256
#define NF 7
#define EF 5
#define NL 5
#define BN_EPS 1e-5f
#define NREP 32     // stats replicas to kill same-line atomic serialization
#define SCAN_B 196  // ceil(NN/256)

typedef __attribute__((ext_vector_type(8))) short bf16x8;
typedef __attribute__((ext_vector_type(4))) float f32x4;

__device__ inline unsigned short f2b(float f) {  // fp32 -> bf16 RNE
    unsigned u = __builtin_bit_cast(unsigned, f);
    return (unsigned short)((u + 0x7fffu + ((u >> 16) & 1u)) >> 16);
}
__device__ inline float b2f(unsigned us) {
    return __builtin_bit_cast(float, us << 16);
}
// split x into hi+lo bf16 pair (packed as 2 cols per unsigned)
__device__ inline void split2(float a, float b, unsigned& hi, unsigned& lo) {
    unsigned short ha = f2b(a), hb = f2b(b);
    unsigned short la = f2b(a - b2f(ha)), lb = f2b(b - b2f(hb));
    hi = (unsigned)ha | ((unsigned)hb << 16);
    lo = (unsigned)la | ((unsigned)lb << 16);
}
// fp16 pack/unpack
__device__ inline unsigned pkh2(float a, float b) {
    union { unsigned v; _Float16 h[2]; } x;
    x.h[0] = (_Float16)a; x.h[1] = (_Float16)b;
    return x.v;
}
__device__ inline float2 uph2(unsigned u) {
    union { unsigned v; _Float16 h[2]; } x; x.v = u;
    return make_float2((float)x.h[0], (float)x.h[1]);
}

// ---------------------------------------------------------------------------
// k_prep: block 0 computes bias-sum vectors; all blocks zero CSR counts/cursor
// and the attsum accumulator.
// ---------------------------------------------------------------------------
__global__ void k_prep(const float* __restrict__ b_x, const float* __restrict__ b_e,
                       float* __restrict__ bsum_x, float* __restrict__ bsum_e,
                       int* __restrict__ counts, int* __restrict__ cursor,
                       float* __restrict__ attsum) {
    int tid = threadIdx.x;
    if (blockIdx.x == 0 && tid < EMB) {
        float s = 0.f;
        for (int f = 0; f < NF; ++f) s += b_x[f * EMB + tid];
        bsum_x[tid] = s;
        for (int l = 0; l < NL; ++l) {
            float se = 0.f;
            for (int f = 0; f < EF; ++f) se += b_e[(l * EF + f) * EMB + tid];
            bsum_e[l * EMB + tid] = se;
        }
    }
    int gid = blockIdx.x * blockDim.x + tid;
    int stride = gridDim.x * blockDim.x;
    for (int i = gid; i < NN; i += stride) { counts[i] = 0; cursor[i] = 0; }
    for (int i = gid; i < NN * 8; i += stride) attsum[i] = 0.f;
}

// ---------------------------------------------------------------------------
// k_prepw: fragment-pack + hi/lo bf16 split of weights.
// W1p layout: [L][wave(4)][h2(4)][kk(4)][lane(64)][j(8)]  (lane-contiguous 16B)
// W2p layout: [L][wave(4)][o2(2)][kk(8)][lane(64)][j(8)]
// ---------------------------------------------------------------------------
__global__ void k_prepw(const float* __restrict__ W1, const float* __restrict__ W2,
                        unsigned short* __restrict__ W1ph, unsigned short* __restrict__ W1pl,
                        unsigned short* __restrict__ W2ph, unsigned short* __restrict__ W2pl) {
    const int TOT = NL * EMB * HID;   // 163840 per matrix
    int gid = blockIdx.x * blockDim.x + threadIdx.x;
    if (gid < TOT) {
        int l = gid / (EMB * HID);
        int r = gid % (EMB * HID);             // 32768
        int w = r >> 13;                       // /8192
        int rem = r & 8191;
        int h2 = rem >> 11;                    // /2048
        int rem2 = rem & 2047;
        int kk = rem2 >> 9;                    // /512
        int rem3 = rem2 & 511;
        int lane = rem3 >> 3;
        int j = rem3 & 7;
        int hc = w * 64 + h2 * 16 + (lane & 15);
        int k = kk * 32 + (lane >> 4) * 8 + j;
        float wv = W1[((size_t)l * EMB + k) * HID + hc];
        unsigned short hi = f2b(wv);
        W1ph[gid] = hi;
        W1pl[gid] = f2b(wv - b2f(hi));
    } else if (gid < 2 * TOT) {
        int g = gid - TOT;
        int l = g / (EMB * HID);
        int r = g % (EMB * HID);
        int w = r >> 13;
        int rem = r & 8191;
        int o2 = rem >> 12;                    // /4096
        int rem2 = rem & 4095;
        int kk = rem2 >> 9;
        int rem3 = rem2 & 511;
        int lane = rem3 >> 3;
        int j = rem3 & 7;
        int oc = w * 32 + o2 * 16 + (lane & 15);
        int k2 = kk * 32 + (lane >> 4) * 8 + j;
        float wv = W2[((size_t)l * HID + k2) * EMB + oc];
        unsigned short hi = f2b(wv);
        W2ph[g] = hi;
        W2pl[g] = f2b(wv - b2f(hi));
    }
}

// ---------------------------------------------------------------------------
// k_init: h(fp16) = x @ W_x + bsum_x  (32 threads/node, 4 cols each)
// ---------------------------------------------------------------------------
__global__ void k_init(const float* __restrict__ x, const float* __restrict__ W_x,
                       const float* __restrict__ bsum_x, unsigned short* __restrict__ h16) {
    int gid = blockIdx.x * blockDim.x + threadIdx.x;
    int v = gid >> 5;
    if (v >= NN) return;
    int c = (gid & 31) << 2;
    float4 acc = *(const float4*)(bsum_x + c);
    #pragma unroll
    for (int f = 0; f < NF; ++f) {
        float xv = x[(size_t)v * NF + f];
        float4 w = *(const float4*)(W_x + f * EMB + c);
        acc.x += xv * w.x; acc.y += xv * w.y; acc.z += xv * w.z; acc.w += xv * w.w;
    }
    uint2 p = make_uint2(pkh2(acc.x, acc.y), pkh2(acc.z, acc.w));
    *(uint2*)(h16 + (size_t)v * EMB + c) = p;
}

// ---------------------------------------------------------------------------
// CSR build: histogram of dst, 3-phase multi-block scan, bucket fill
// ---------------------------------------------------------------------------
__global__ void k_hist(const int* __restrict__ dst, int* __restrict__ counts) {
    int e = blockIdx.x * blockDim.x + threadIdx.x;
    if (e < NE) atomicAdd(&counts[dst[e]], 1);
}

__global__ void k_scan1(const int* __restrict__ counts, int* __restrict__ bsum) {
    int tid = threadIdx.x;
    int i = blockIdx.x * 256 + tid;
    int v = (i < NN) ? counts[i] : 0;
    #pragma unroll
    for (int off = 1; off < 64; off <<= 1) v += __shfl_xor(v, off, 64);
    __shared__ int ws[4];
    if ((tid & 63) == 0) ws[tid >> 6] = v;
    __syncthreads();
    if (tid == 0) bsum[blockIdx.x] = ws[0] + ws[1] + ws[2] + ws[3];
}

__global__ void k_scan2(const int* __restrict__ bsum, int* __restrict__ bpre,
                        int* __restrict__ row_start) {
    int tid = threadIdx.x;  // 256 threads
    int x = (tid < SCAN_B) ? bsum[tid] : 0;
    int lane = tid & 63, wv = tid >> 6;
    int v = x;
    #pragma unroll
    for (int off = 1; off < 64; off <<= 1) {
        int t = __shfl_up(v, off, 64);
        if (lane >= off) v += t;
    }
    __shared__ int wsum[4];
    if (lane == 63) wsum[wv] = v;
    __syncthreads();
    int woff = 0;
    #pragma unroll
    for (int w = 0; w < 4; ++w) if (w < wv) woff += wsum[w];
    int incl = v + woff;
    if (tid < SCAN_B) bpre[tid] = incl - x;
    if (tid == 255) row_start[NN] = incl;
}

__global__ void k_scan3(const int* __restrict__ counts, const int* __restrict__ bpre,
                        int* __restrict__ row_start) {
    int tid = threadIdx.x;
    int i = blockIdx.x * 256 + tid;
    int x = (i < NN) ? counts[i] : 0;
    int lane = tid & 63, wv = tid >> 6;
    int v = x;
    #pragma unroll
    for (int off = 1; off < 64; off <<= 1) {
        int t = __shfl_up(v, off, 64);
        if (lane >= off) v += t;
    }
    __shared__ int wsum[4];
    if (lane == 63) wsum[wv] = v;
    __syncthreads();
    int woff = 0;
    #pragma unroll
    for (int w = 0; w < 4; ++w) if (w < wv) woff += wsum[w];
    if (i < NN) row_start[i] = bpre[blockIdx.x] + v + woff - x;
}

// ---------------------------------------------------------------------------
// k_fill: 4-B src scatter (CSR bucket) + direct fp32 atomic accumulation of
// per-node edge-attr sums (replaces the 16-B packed scatter + k_esum pass).
// ---------------------------------------------------------------------------
__global__ void k_fill(const int* __restrict__ src, const int* __restrict__ dst,
                       const float* __restrict__ edge_attr,
                       const int* __restrict__ row_start, int* __restrict__ cursor,
                       int* __restrict__ sorted_srcc, float* __restrict__ attsum) {
    int e = blockIdx.x * blockDim.x + threadIdx.x;
    if (e >= NE) return;
    int d = dst[e];
    int pos = atomicAdd(&cursor[d], 1);
    sorted_srcc[row_start[d] + pos] = src[e];
    const float* ea = edge_attr + (size_t)e * EF;
    float* ap = attsum + (size_t)d * 8;
    atomicAdd(ap + 0, ea[0]);
    atomicAdd(ap + 1, ea[1]);
    atomicAdd(ap + 2, ea[2]);
    atomicAdd(ap + 3, ea[3]);
    atomicAdd(ap + 4, ea[4]);
}

// ---------------------------------------------------------------------------
// k_agg<APPLY_BN>: agg[v] = state(v) + (deg+1)*bs + attsum[v]@W_e + sum_e state(src)
// state(u) = APPLY_BN ? ELU(z16[u]*sc+sh) : h16[u].
// Lane map: li=lane&15 owns cols [li*8,li*8+8) (16 B of the 256-B row);
// eg=lane>>4 is the edge slot -> ONE dwordx4 VMEM inst covers 4 edges (4x fewer
// gather instructions + address VALU than the 2-col map). Main loop: 16 edges,
// 4 independent gathers in flight. shfl_xor(16/32) folds edge slots; eg==0
// stores the hi/lo bf16 planes (format unchanged for k_mlp).
// Blocks 0..31 zero the BN-stats replicas for this layer.
// ---------------------------------------------------------------------------
template<int APPLY_BN>
__global__ __launch_bounds__(256) void k_agg(
        const unsigned short* __restrict__ st16, const int* __restrict__ sorted_srcc,
        const float* __restrict__ attsum, const float* __restrict__ scsh,
        const float* __restrict__ W_e_l, const float* __restrict__ bsum_e_l,
        const int* __restrict__ row_start,
        unsigned* __restrict__ agg_hi, unsigned* __restrict__ agg_lo,
        float* __restrict__ stats) {
    int tid = threadIdx.x;
    if (blockIdx.x < NREP) stats[blockIdx.x * 2 * EMB + tid] = 0.f;  // 256 == 2*EMB
    int gid = blockIdx.x * 256 + tid;
    int v = gid >> 6;
    if (v >= NN) return;
    int lane = tid & 63;
    int li = lane & 15;      // col group: cols [li*8, li*8+8)
    int eg = lane >> 4;      // edge slot 0..3
    int cb = li * 8;
    float scv[8], shv[8];
    if (APPLY_BN) {
        float4 s0 = *(const float4*)(scsh + cb);
        float4 s1 = *(const float4*)(scsh + cb + 4);
        float4 t0 = *(const float4*)(scsh + EMB + cb);
        float4 t1 = *(const float4*)(scsh + EMB + cb + 4);
        scv[0]=s0.x; scv[1]=s0.y; scv[2]=s0.z; scv[3]=s0.w;
        scv[4]=s1.x; scv[5]=s1.y; scv[6]=s1.z; scv[7]=s1.w;
        shv[0]=t0.x; shv[1]=t0.y; shv[2]=t0.z; shv[3]=t0.w;
        shv[4]=t1.x; shv[5]=t1.y; shv[6]=t1.z; shv[7]=t1.w;
    }
    float acc[8] = {0.f,0.f,0.f,0.f,0.f,0.f,0.f,0.f};
    auto accum8 = [&](uint4 u) {
        float2 p0 = uph2(u.x), p1 = uph2(u.y), p2 = uph2(u.z), p3 = uph2(u.w);
        float t[8] = {p0.x, p0.y, p1.x, p1.y, p2.x, p2.y, p3.x, p3.y};
        #pragma unroll
        for (int j = 0; j < 8; ++j) {
            float xx = t[j];
            if (APPLY_BN) {
                xx = xx * scv[j] + shv[j];
                xx = (xx > 0.f) ? xx : (__expf(xx) - 1.f);
            }
            acc[j] += xx;
        }
    };
    int e0 = row_start[v], e1 = row_start[v + 1];
    int e = e0;
    for (; e + 16 <= e1; e += 16) {
        int sA = sorted_srcc[e + eg];
        int sB = sorted_srcc[e + 4 + eg];
        int sC = sorted_srcc[e + 8 + eg];
        int sD = sorted_srcc[e + 12 + eg];
        uint4 uA = *(const uint4*)(st16 + (size_t)sA * EMB + cb);
        uint4 uB = *(const uint4*)(st16 + (size_t)sB * EMB + cb);
        uint4 uC = *(const uint4*)(st16 + (size_t)sC * EMB + cb);
        uint4 uD = *(const uint4*)(st16 + (size_t)sD * EMB + cb);
        accum8(uA); accum8(uB); accum8(uC); accum8(uD);
    }
    for (; e < e1; e += 4) {
        int ee = e + eg;
        if (ee < e1) {
            int s = sorted_srcc[ee];
            uint4 u = *(const uint4*)(st16 + (size_t)s * EMB + cb);
            accum8(u);
        }
    }
    // fold the 4 edge slots (lane^16, lane^32)
    #pragma unroll
    for (int j = 0; j < 8; ++j) {
        acc[j] += __shfl_xor(acc[j], 16, 64);
        acc[j] += __shfl_xor(acc[j], 32, 64);
    }
    // epilogue: self + (deg+1)*bs + attsum@W_e  (redundant across eg groups)
    float deg = (float)(e1 - e0);
    const float* at = attsum + (size_t)v * 8;
    float4 a03 = *(const float4*)(at);
    float a4 = at[4];
    uint4 su = *(const uint4*)(st16 + (size_t)v * EMB + cb);
    float2 q0 = uph2(su.x), q1 = uph2(su.y), q2 = uph2(su.z), q3 = uph2(su.w);
    float sf[8] = {q0.x, q0.y, q1.x, q1.y, q2.x, q2.y, q3.x, q3.y};
    if (APPLY_BN) {
        #pragma unroll
        for (int j = 0; j < 8; ++j) {
            float xx = sf[j] * scv[j] + shv[j];
            sf[j] = (xx > 0.f) ? xx : (__expf(xx) - 1.f);
        }
    }
    float out[8];
    #pragma unroll
    for (int half = 0; half < 2; ++half) {
        int cbh = cb + half * 4;
        float4 bsv = *(const float4*)(bsum_e_l + cbh);
        float4 w0 = *(const float4*)(W_e_l + 0 * EMB + cbh);
        float4 w1 = *(const float4*)(W_e_l + 1 * EMB + cbh);
        float4 w2 = *(const float4*)(W_e_l + 2 * EMB + cbh);
        float4 w3 = *(const float4*)(W_e_l + 3 * EMB + cbh);
        float4 w4 = *(const float4*)(W_e_l + 4 * EMB + cbh);
        const float* bsp = (const float*)&bsv;
        const float* w0p = (const float*)&w0;
        const float* w1p = (const float*)&w1;
        const float* w2p = (const float*)&w2;
        const float* w3p = (const float*)&w3;
        const float* w4p = (const float*)&w4;
        #pragma unroll
        for (int j = 0; j < 4; ++j) {
            int jj = half * 4 + j;
            out[jj] = acc[jj] + sf[jj] + (deg + 1.f) * bsp[j]
                    + a03.x * w0p[j] + a03.y * w1p[j] + a03.z * w2p[j]
                    + a03.w * w3p[j] + a4 * w4p[j];
        }
    }
    if (eg == 0) {
        uint4 hi, lo;
        split2(out[0], out[1], hi.x, lo.x);
        split2(out[2], out[3], hi.y, lo.y);
        split2(out[4], out[5], hi.z, lo.z);
        split2(out[6], out[7], hi.w, lo.w);
        *(uint4*)(agg_hi + (size_t)v * 64 + li * 4) = hi;
        *(uint4*)(agg_lo + (size_t)v * 64 + li * 4) = lo;
    }
}

// ---------------------------------------------------------------------------
// k_mlp (MFMA, hi/lo split = fp32-accurate), fragment-packed weights.
// 32-row tile, 4 waves. D-frag: col=lane&15 (node), row=quad*4+reg.
// Writes z as fp16. BN stats -> replicated buffers (blockIdx&31).
// ---------------------------------------------------------------------------
__global__ __launch_bounds__(256) void k_mlp(
        const unsigned short* __restrict__ aggh, const unsigned short* __restrict__ aggl,
        const unsigned short* __restrict__ W1ph, const unsigned short* __restrict__ W1pl,
        const float* __restrict__ b1_l,
        const unsigned short* __restrict__ W2ph, const unsigned short* __restrict__ W2pl,
        const float* __restrict__ b2_l,
        unsigned short* __restrict__ z16, float* __restrict__ stats) {
    __shared__ unsigned short Ahi[32][136];   // 8.5 KB  (+8 pad)
    __shared__ unsigned short Alo[32][136];   // 8.5 KB
    __shared__ unsigned short Hhi[32][264];   // 16.5 KB (+8 pad)
    __shared__ unsigned short Hlo[32][264];   // 16.5 KB
    int tid = threadIdx.x;
    int r0 = blockIdx.x * 32;
    int rep = blockIdx.x & (NREP - 1);
    // stage A hi/lo tiles (zero-pad rows >= NN)
    #pragma unroll
    for (int it = 0; it < 4; ++it) {
        int idx = it * 256 + tid;       // 0..1023
        int plane = idx >> 9;
        int k = idx & 511;
        int row = k >> 4;
        int cb = (k & 15) * 8;
        int grow = r0 + row;
        uint4 val = make_uint4(0u, 0u, 0u, 0u);
        const unsigned short* srcp = plane ? aggl : aggh;
        if (grow < NN) val = *(const uint4*)(srcp + (size_t)grow * EMB + cb);
        if (plane) *(uint4*)(&Alo[row][cb]) = val;
        else       *(uint4*)(&Ahi[row][cb]) = val;
    }
    __syncthreads();
    int wave = tid >> 6, lane = tid & 63;
    int l16 = lane & 15, quad = lane >> 4;
    // ---- phase 1: wave owns hid cols [64*wave, 64*wave+64)
    {
        bf16x8 ahi[2][4], alo[2][4];
        #pragma unroll
        for (int nt = 0; nt < 2; ++nt)
            #pragma unroll
            for (int kk = 0; kk < 4; ++kk) {
                ahi[nt][kk] = *(const bf16x8*)(&Ahi[nt * 16 + l16][kk * 32 + quad * 8]);
                alo[nt][kk] = *(const bf16x8*)(&Alo[nt * 16 + l16][kk * 32 + quad * 8]);
            }
        #pragma unroll
        for (int h2 = 0; h2 < 4; ++h2) {
            bf16x8 whi[4], wlo[4];
            #pragma unroll
            for (int kk = 0; kk < 4; ++kk) {
                size_t off = ((((size_t)(wave * 4 + h2) * 4) + kk) * 64 + lane) * 8;
                whi[kk] = *(const bf16x8*)(W1ph + off);
                wlo[kk] = *(const bf16x8*)(W1pl + off);
            }
            float4 bv = *(const float4*)(b1_l + wave * 64 + h2 * 16 + quad * 4);
            f32x4 bias = {bv.x, bv.y, bv.z, bv.w};
            #pragma unroll
            for (int nt = 0; nt < 2; ++nt) {
                f32x4 acc = bias;
                #pragma unroll
                for (int kk = 0; kk < 4; ++kk)
                    acc = __builtin_amdgcn_mfma_f32_16x16x32_bf16(whi[kk], ahi[nt][kk], acc, 0, 0, 0);
                #pragma unroll
                for (int kk = 0; kk < 4; ++kk)
                    acc = __builtin_amdgcn_mfma_f32_16x16x32_bf16(whi[kk], alo[nt][kk], acc, 0, 0, 0);
                #pragma unroll
                for (int kk = 0; kk < 4; ++kk)
                    acc = __builtin_amdgcn_mfma_f32_16x16x32_bf16(wlo[kk], ahi[nt][kk], acc, 0, 0, 0);
                float v0 = fmaxf(acc[0], 0.f), v1 = fmaxf(acc[1], 0.f);
                float v2 = fmaxf(acc[2], 0.f), v3 = fmaxf(acc[3], 0.f);
                unsigned hiA, loA, hiB, loB;
                split2(v0, v1, hiA, loA);
                split2(v2, v3, hiB, loB);
                int col = wave * 64 + h2 * 16 + quad * 4;
                *(uint2*)(&Hhi[nt * 16 + l16][col]) = make_uint2(hiA, hiB);
                *(uint2*)(&Hlo[nt * 16 + l16][col]) = make_uint2(loA, loB);
            }
        }
    }
    __syncthreads();
    // ---- phase 2: wave owns out cols [32*wave, 32*wave+32)
    float ss[2][4] = {}, sq[2][4] = {};
    #pragma unroll
    for (int o2 = 0; o2 < 2; ++o2) {
        bf16x8 w2h[8], w2l[8];
        #pragma unroll
        for (int kk = 0; kk < 8; ++kk) {
            size_t off = ((((size_t)(wave * 2 + o2) * 8) + kk) * 64 + lane) * 8;
            w2h[kk] = *(const bf16x8*)(W2ph + off);
            w2l[kk] = *(const bf16x8*)(W2pl + off);
        }
        float4 bv = *(const float4*)(b2_l + wave * 32 + o2 * 16 + quad * 4);
        f32x4 bias = {bv.x, bv.y, bv.z, bv.w};
        #pragma unroll
        for (int nt = 0; nt < 2; ++nt) {
            bf16x8 hh[8], hl[8];
            #pragma unroll
            for (int kk = 0; kk < 8; ++kk) {
                hh[kk] = *(const bf16x8*)(&Hhi[nt * 16 + l16][kk * 32 + quad * 8]);
                hl[kk] = *(const bf16x8*)(&Hlo[nt * 16 + l16][kk * 32 + quad * 8]);
            }
            f32x4 acc = bias;
            #pragma unroll
            for (int kk = 0; kk < 8; ++kk)
                acc = __builtin_amdgcn_mfma_f32_16x16x32_bf16(w2h[kk], hh[kk], acc, 0, 0, 0);
            #pragma unroll
            for (int kk = 0; kk < 8; ++kk)
                acc = __builtin_amdgcn_mfma_f32_16x16x32_bf16(w2h[kk], hl[kk], acc, 0, 0, 0);
            #pragma unroll
            for (int kk = 0; kk < 8; ++kk)
                acc = __builtin_amdgcn_mfma_f32_16x16x32_bf16(w2l[kk], hh[kk], acc, 0, 0, 0);
            int node = r0 + nt * 16 + l16;
            if (node < NN) {
                uint2 p = make_uint2(pkh2(acc[0], acc[1]), pkh2(acc[2], acc[3]));
                *(uint2*)(z16 + (size_t)node * EMB + wave * 32 + o2 * 16 + quad * 4) = p;
                #pragma unroll
                for (int r = 0; r < 4; ++r) {
                    ss[o2][r] += acc[r];
                    sq[o2][r] += acc[r] * acc[r];
                }
            }
        }
    }
    #pragma unroll
    for (int o2 = 0; o2 < 2; ++o2)
        #pragma unroll
        for (int r = 0; r < 4; ++r) {
            float s = ss[o2][r], q = sq[o2][r];
            #pragma unroll
            for (int m = 1; m < 16; m <<= 1) {
                s += __shfl_xor(s, m, 64);
                q += __shfl_xor(q, m, 64);
            }
            if (l16 == 0) {
                int oc = wave * 32 + o2 * 16 + quad * 4 + r;
                atomicAdd(&stats[rep * 2 * EMB + oc], s);
                atomicAdd(&stats[rep * 2 * EMB + EMB + oc], q);
            }
        }
}

// ---------------------------------------------------------------------------
// k_bnscale: ONE block reduces the NREP stats replicas -> sc/sh (1 KB).
// (Next layer's k_agg re-zeroes the replicas.)
// ---------------------------------------------------------------------------
__global__ void k_bnscale(const float* __restrict__ stats,
                          const float* __restrict__ gamma_l, const float* __restrict__ beta_l,
                          float* __restrict__ scsh) {
    int tid = threadIdx.x;  // 128 threads
    float s = 0.f, q = 0.f;
    #pragma unroll
    for (int r = 0; r < NREP; ++r) {
        s += stats[r * 2 * EMB + tid];
        q += stats[r * 2 * EMB + EMB + tid];
    }
    float mu = s * (1.f / NN);
    float var = q * (1.f / NN) - mu * mu;
    float sf = gamma_l[tid] * rsqrtf(var + BN_EPS);
    scsh[tid] = sf;
    scsh[EMB + tid] = beta_l[tid] - mu * sf;
}

// ---------------------------------------------------------------------------
// k_bn (final layer only): z16 -> fp32 z*sc + sh into d_out.
// ---------------------------------------------------------------------------
__global__ void k_bn(const unsigned short* __restrict__ z16, const float* __restrict__ scsh,
                     float* __restrict__ fout) {
    __shared__ float sc[EMB], sh[EMB];
    int tid = threadIdx.x;
    if (tid < EMB) {
        sc[tid] = scsh[tid];
        sh[tid] = scsh[EMB + tid];
    }
    __syncthreads();
    int gid = blockIdx.x * blockDim.x + tid;
    if (gid >= NN * EMB / 4) return;
    int c = (gid & 31) << 2;
    uint2 zp = *(const uint2*)(z16 + (size_t)gid * 4);
    float2 z01 = uph2(zp.x), z23 = uph2(zp.y);
    float o0 = z01.x * sc[c + 0] + sh[c + 0];
    float o1 = z01.y * sc[c + 1] + sh[c + 1];
    float o2 = z23.x * sc[c + 2] + sh[c + 2];
    float o3 = z23.y * sc[c + 3] + sh[c + 3];
    *(float4*)(fout + (size_t)gid * 4) = make_float4(o0, o1, o2, o3);
}

// ---------------------------------------------------------------------------
extern "C" void kernel_launch(void* const* d_in, const int* in_sizes, int n_in,
                              void* d_out, int out_size, void* d_ws, size_t ws_size,
                              hipStream_t stream) {
    const float* x         = (const float*)d_in[0];
    const float* edge_attr = (const float*)d_in[1];
    const int*   edge_idx  = (const int*)d_in[2];
    const float* W_x   = (const float*)d_in[3];
    const float* b_x   = (const float*)d_in[4];
    const float* W_e   = (const float*)d_in[5];
    const float* b_e   = (const float*)d_in[6];
    const float* W1    = (const float*)d_in[7];
    const float* b1    = (const float*)d_in[8];
    const float* W2    = (const float*)d_in[9];
    const float* b2    = (const float*)d_in[10];
    const float* gamma = (const float*)d_in[11];
    const float* beta  = (const float*)d_in[12];
    float* fout = (float*)d_out;  // final BN writes fp32 here

    const int* src = edge_idx;
    const int* dst = edge_idx + NE;

    char* p = (char*)d_ws;
    auto alloc = [&](size_t bytes) { char* q = p; p += (bytes + 255) & ~(size_t)255; return q; };
    unsigned short* h16 = (unsigned short*)alloc((size_t)NN * EMB * 2);
    unsigned short* z16 = (unsigned short*)alloc((size_t)NN * EMB * 2);
    unsigned* agg_hi = (unsigned*)alloc((size_t)NN * EMB * 2);
    unsigned* agg_lo = (unsigned*)alloc((size_t)NN * EMB * 2);
    unsigned short* W1ph = (unsigned short*)alloc((size_t)NL * HID * EMB * 2);
    unsigned short* W1pl = (unsigned short*)alloc((size_t)NL * HID * EMB * 2);
    unsigned short* W2ph = (unsigned short*)alloc((size_t)NL * EMB * HID * 2);
    unsigned short* W2pl = (unsigned short*)alloc((size_t)NL * EMB * HID * 2);
    int*   row_start  = (int*)alloc((NN + 1) * sizeof(int));
    int*   counts     = (int*)alloc(NN * sizeof(int));
    int*   cursor     = (int*)alloc(NN * sizeof(int));
    int*   sorted_srcc= (int*)alloc((size_t)NE * sizeof(int));
    float* attsum     = (float*)alloc((size_t)NN * 8 * sizeof(float));
    int*   bsum       = (int*)alloc(SCAN_B * sizeof(int));
    int*   bpre       = (int*)alloc(SCAN_B * sizeof(int));
    float* stats      = (float*)alloc((size_t)NREP * 2 * EMB * sizeof(float));
    float* scsh       = (float*)alloc(2 * EMB * sizeof(float));
    float* bsum_x     = (float*)alloc(EMB * sizeof(float));
    float* bsum_e     = (float*)alloc(NL * EMB * sizeof(float));

    k_prep<<<256, 256, 0, stream>>>(b_x, b_e, bsum_x, bsum_e, counts, cursor, attsum);
    k_prepw<<<(2 * NL * EMB * HID + 255) / 256, 256, 0, stream>>>(W1, W2, W1ph, W1pl, W2ph, W2pl);
    k_init<<<(NN * 32 + 255) / 256, 256, 0, stream>>>(x, W_x, bsum_x, h16);
    k_hist<<<(NE + 255) / 256, 256, 0, stream>>>(dst, counts);
    k_scan1<<<SCAN_B, 256, 0, stream>>>(counts, bsum);
    k_scan2<<<1, 256, 0, stream>>>(bsum, bpre, row_start);
    k_scan3<<<SCAN_B, 256, 0, stream>>>(counts, bpre, row_start);
    k_fill<<<(NE + 255) / 256, 256, 0, stream>>>(src, dst, edge_attr, row_start, cursor,
                                                 sorted_srcc, attsum);
    const int AGG_GRID = (NN * 64 + 255) / 256;
    for (int l = 0; l < NL; ++l) {
        if (l == 0) {
            k_agg<0><<<AGG_GRID, 256, 0, stream>>>(
                h16, sorted_srcc, attsum, scsh,
                W_e + (size_t)l * EF * EMB, bsum_e + l * EMB, row_start,
                agg_hi, agg_lo, stats);
        } else {
            k_agg<1><<<AGG_GRID, 256, 0, stream>>>(
                z16, sorted_srcc, attsum, scsh,
                W_e + (size_t)l * EF * EMB, bsum_e + l * EMB, row_start,
                agg_hi, agg_lo, stats);
        }
        k_mlp<<<(NN + 31) / 32, 256, 0, stream>>>(
            (const unsigned short*)agg_hi, (const unsigned short*)agg_lo,
            W1ph + (size_t)l * HID * EMB, W1pl + (size_t)l * HID * EMB, b1 + (size_t)l * HID,
            W2ph + (size_t)l * EMB * HID, W2pl + (size_t)l * EMB * HID, b2 + (size_t)l * EMB,
            z16, stats);
        k_bnscale<<<1, 128, 0, stream>>>(stats, gamma + l * EMB, beta + l * EMB, scsh);
    }
    k_bn<<<(NN * EMB / 4 + 255) / 256, 256, 0, stream>>>(z16, scsh, fout);
}

// Round 12
// 666.118 us; speedup vs baseline: 1.2894x; 1.2894x over previous
//
#include <hip/hip_runtime.h>
#include <math.h>

#define NN 50000
#define NE 800000
#define EMB 128
#define HID 256
#define NF 7
#define EF 5
#define NL 5
#define BN_EPS 1e-5f
#define NREP 32     // stats replicas to kill same-line atomic serialization
#define SCAN_B 196  // ceil(NN/256)

typedef __attribute__((ext_vector_type(8))) short bf16x8;
typedef __attribute__((ext_vector_type(4))) float f32x4;

__device__ inline unsigned short f2b(float f) {  // fp32 -> bf16 RNE
    unsigned u = __builtin_bit_cast(unsigned, f);
    return (unsigned short)((u + 0x7fffu + ((u >> 16) & 1u)) >> 16);
}
__device__ inline float b2f(unsigned us) {
    return __builtin_bit_cast(float, us << 16);
}
// split x into hi+lo bf16 pair (packed as 2 cols per unsigned)
__device__ inline void split2(float a, float b, unsigned& hi, unsigned& lo) {
    unsigned short ha = f2b(a), hb = f2b(b);
    unsigned short la = f2b(a - b2f(ha)), lb = f2b(b - b2f(hb));
    hi = (unsigned)ha | ((unsigned)hb << 16);
    lo = (unsigned)la | ((unsigned)lb << 16);
}
// fp16 pack/unpack
__device__ inline unsigned pkh2(float a, float b) {
    union { unsigned v; _Float16 h[2]; } x;
    x.h[0] = (_Float16)a; x.h[1] = (_Float16)b;
    return x.v;
}
__device__ inline float2 uph2(unsigned u) {
    union { unsigned v; _Float16 h[2]; } x; x.v = u;
    return make_float2((float)x.h[0], (float)x.h[1]);
}

// ---------------------------------------------------------------------------
// k_prep: block 0 computes bias-sum vectors; all blocks zero CSR counts/cursor
// ---------------------------------------------------------------------------
__global__ void k_prep(const float* __restrict__ b_x, const float* __restrict__ b_e,
                       float* __restrict__ bsum_x, float* __restrict__ bsum_e,
                       int* __restrict__ counts, int* __restrict__ cursor) {
    int tid = threadIdx.x;
    if (blockIdx.x == 0 && tid < EMB) {
        float s = 0.f;
        for (int f = 0; f < NF; ++f) s += b_x[f * EMB + tid];
        bsum_x[tid] = s;
        for (int l = 0; l < NL; ++l) {
            float se = 0.f;
            for (int f = 0; f < EF; ++f) se += b_e[(l * EF + f) * EMB + tid];
            bsum_e[l * EMB + tid] = se;
        }
    }
    int gid = blockIdx.x * blockDim.x + tid;
    int stride = gridDim.x * blockDim.x;
    for (int i = gid; i < NN; i += stride) { counts[i] = 0; cursor[i] = 0; }
}

// ---------------------------------------------------------------------------
// k_prepw: fragment-pack + hi/lo bf16 split of weights.
// W1p layout: [L][wave(4)][h2(4)][kk(4)][lane(64)][j(8)]  (lane-contiguous 16B)
// W2p layout: [L][wave(4)][o2(2)][kk(8)][lane(64)][j(8)]
// ---------------------------------------------------------------------------
__global__ void k_prepw(const float* __restrict__ W1, const float* __restrict__ W2,
                        unsigned short* __restrict__ W1ph, unsigned short* __restrict__ W1pl,
                        unsigned short* __restrict__ W2ph, unsigned short* __restrict__ W2pl) {
    const int TOT = NL * EMB * HID;   // 163840 per matrix
    int gid = blockIdx.x * blockDim.x + threadIdx.x;
    if (gid < TOT) {
        int l = gid / (EMB * HID);
        int r = gid % (EMB * HID);             // 32768
        int w = r >> 13;                       // /8192
        int rem = r & 8191;
        int h2 = rem >> 11;                    // /2048
        int rem2 = rem & 2047;
        int kk = rem2 >> 9;                    // /512
        int rem3 = rem2 & 511;
        int lane = rem3 >> 3;
        int j = rem3 & 7;
        int hc = w * 64 + h2 * 16 + (lane & 15);
        int k = kk * 32 + (lane >> 4) * 8 + j;
        float wv = W1[((size_t)l * EMB + k) * HID + hc];
        unsigned short hi = f2b(wv);
        W1ph[gid] = hi;
        W1pl[gid] = f2b(wv - b2f(hi));
    } else if (gid < 2 * TOT) {
        int g = gid - TOT;
        int l = g / (EMB * HID);
        int r = g % (EMB * HID);
        int w = r >> 13;
        int rem = r & 8191;
        int o2 = rem >> 12;                    // /4096
        int rem2 = rem & 4095;
        int kk = rem2 >> 9;
        int rem3 = rem2 & 511;
        int lane = rem3 >> 3;
        int j = rem3 & 7;
        int oc = w * 32 + o2 * 16 + (lane & 15);
        int k2 = kk * 32 + (lane >> 4) * 8 + j;
        float wv = W2[((size_t)l * HID + k2) * EMB + oc];
        unsigned short hi = f2b(wv);
        W2ph[g] = hi;
        W2pl[g] = f2b(wv - b2f(hi));
    }
}

// ---------------------------------------------------------------------------
// k_init: h(fp16) = x @ W_x + bsum_x  (32 threads/node, 4 cols each)
// ---------------------------------------------------------------------------
__global__ void k_init(const float* __restrict__ x, const float* __restrict__ W_x,
                       const float* __restrict__ bsum_x, unsigned short* __restrict__ h16) {
    int gid = blockIdx.x * blockDim.x + threadIdx.x;
    int v = gid >> 5;
    if (v >= NN) return;
    int c = (gid & 31) << 2;
    float4 acc = *(const float4*)(bsum_x + c);
    #pragma unroll
    for (int f = 0; f < NF; ++f) {
        float xv = x[(size_t)v * NF + f];
        float4 w = *(const float4*)(W_x + f * EMB + c);
        acc.x += xv * w.x; acc.y += xv * w.y; acc.z += xv * w.z; acc.w += xv * w.w;
    }
    uint2 p = make_uint2(pkh2(acc.x, acc.y), pkh2(acc.z, acc.w));
    *(uint2*)(h16 + (size_t)v * EMB + c) = p;
}

// ---------------------------------------------------------------------------
// CSR build: histogram of dst, 3-phase multi-block scan, packed bucket fill
// ---------------------------------------------------------------------------
__global__ void k_hist(const int* __restrict__ dst, int* __restrict__ counts) {
    int e = blockIdx.x * blockDim.x + threadIdx.x;
    if (e < NE) atomicAdd(&counts[dst[e]], 1);
}

__global__ void k_scan1(const int* __restrict__ counts, int* __restrict__ bsum) {
    int tid = threadIdx.x;
    int i = blockIdx.x * 256 + tid;
    int v = (i < NN) ? counts[i] : 0;
    #pragma unroll
    for (int off = 1; off < 64; off <<= 1) v += __shfl_xor(v, off, 64);
    __shared__ int ws[4];
    if ((tid & 63) == 0) ws[tid >> 6] = v;
    __syncthreads();
    if (tid == 0) bsum[blockIdx.x] = ws[0] + ws[1] + ws[2] + ws[3];
}

__global__ void k_scan2(const int* __restrict__ bsum, int* __restrict__ bpre,
                        int* __restrict__ row_start) {
    int tid = threadIdx.x;  // 256 threads
    int x = (tid < SCAN_B) ? bsum[tid] : 0;
    int lane = tid & 63, wv = tid >> 6;
    int v = x;
    #pragma unroll
    for (int off = 1; off < 64; off <<= 1) {
        int t = __shfl_up(v, off, 64);
        if (lane >= off) v += t;
    }
    __shared__ int wsum[4];
    if (lane == 63) wsum[wv] = v;
    __syncthreads();
    int woff = 0;
    #pragma unroll
    for (int w = 0; w < 4; ++w) if (w < wv) woff += wsum[w];
    int incl = v + woff;
    if (tid < SCAN_B) bpre[tid] = incl - x;
    if (tid == 255) row_start[NN] = incl;
}

__global__ void k_scan3(const int* __restrict__ counts, const int* __restrict__ bpre,
                        int* __restrict__ row_start) {
    int tid = threadIdx.x;
    int i = blockIdx.x * 256 + tid;
    int x = (i < NN) ? counts[i] : 0;
    int lane = tid & 63, wv = tid >> 6;
    int v = x;
    #pragma unroll
    for (int off = 1; off < 64; off <<= 1) {
        int t = __shfl_up(v, off, 64);
        if (lane >= off) v += t;
    }
    __shared__ int wsum[4];
    if (lane == 63) wsum[wv] = v;
    __syncthreads();
    int woff = 0;
    #pragma unroll
    for (int w = 0; w < 4; ++w) if (w < wv) woff += wsum[w];
    if (i < NN) row_start[i] = bpre[blockIdx.x] + v + woff - x;
}

// k_fill: ONE 16-B scatter per edge: {src, fp16 ea0..ea4}  (known-good: ~52us,
// WRITE ~51MB; scattered per-edge atomics to attsum were 237us — reverted).
__global__ void k_fill(const int* __restrict__ src, const int* __restrict__ dst,
                       const float* __restrict__ edge_attr,
                       const int* __restrict__ row_start, int* __restrict__ cursor,
                       uint4* __restrict__ sorted_pk) {
    int e = blockIdx.x * blockDim.x + threadIdx.x;
    if (e >= NE) return;
    int d = dst[e];
    int pos = atomicAdd(&cursor[d], 1);
    int idx = row_start[d] + pos;
    const float* ea = edge_attr + (size_t)e * EF;
    float a0 = ea[0], a1 = ea[1], a2 = ea[2], a3 = ea[3], a4 = ea[4];
    uint4 pk;
    pk.x = (unsigned)src[e];
    pk.y = pkh2(a0, a1);
    pk.z = pkh2(a2, a3);
    pk.w = pkh2(a4, 0.f);
    sorted_pk[idx] = pk;
}

// ---------------------------------------------------------------------------
// k_esum (once): per node, sum incoming edge attrs -> attsum[v][8] =
// {a0..a4, deg, 0, 0}; emit compact sorted_srcc[e] (sequential write).
// ---------------------------------------------------------------------------
__global__ void k_esum(const uint4* __restrict__ sorted_pk,
                       const int* __restrict__ row_start,
                       float* __restrict__ attsum, int* __restrict__ sorted_srcc) {
    int v = blockIdx.x * blockDim.x + threadIdx.x;
    if (v >= NN) return;
    int e0 = row_start[v], e1 = row_start[v + 1];
    float s0 = 0.f, s1 = 0.f, s2 = 0.f, s3 = 0.f, s4 = 0.f;
    for (int e = e0; e < e1; ++e) {
        uint4 pk = sorted_pk[e];
        sorted_srcc[e] = (int)pk.x;
        float2 a01 = uph2(pk.y), a23 = uph2(pk.z), a4x = uph2(pk.w);
        s0 += a01.x; s1 += a01.y; s2 += a23.x; s3 += a23.y; s4 += a4x.x;
    }
    float* o = attsum + (size_t)v * 8;
    *(float4*)(o) = make_float4(s0, s1, s2, s3);
    *(float4*)(o + 4) = make_float4(s4, (float)(e1 - e0), 0.f, 0.f);
}

// ---------------------------------------------------------------------------
// k_agg<APPLY_BN>: agg[v] = state(v) + (deg+1)*bs + attsum[v]@W_e + sum_e state(src)
// state(u) = APPLY_BN ? ELU(z16[u]*sc+sh) : h16[u].
// Lane map: li=lane&15 owns cols [li*8,li*8+8); eg=lane>>4 is the edge slot ->
// one dwordx4 VMEM inst covers 4 edges. Main loop: 16 edges, 4 gathers in
// flight. TAIL now also issues all (<=4) guarded gathers independently before
// accumulating — round-11's depth-1 tail was the latency exposure.
// shfl_xor(16/32) folds edge slots; eg==0 stores hi/lo planes.
// Blocks 0..31 zero the BN-stats replicas for this layer.
// ---------------------------------------------------------------------------
template<int APPLY_BN>
__global__ __launch_bounds__(256) void k_agg(
        const unsigned short* __restrict__ st16, const int* __restrict__ sorted_srcc,
        const float* __restrict__ attsum, const float* __restrict__ scsh,
        const float* __restrict__ W_e_l, const float* __restrict__ bsum_e_l,
        const int* __restrict__ row_start,
        unsigned* __restrict__ agg_hi, unsigned* __restrict__ agg_lo,
        float* __restrict__ stats) {
    int tid = threadIdx.x;
    if (blockIdx.x < NREP) stats[blockIdx.x * 2 * EMB + tid] = 0.f;  // 256 == 2*EMB
    int gid = blockIdx.x * 256 + tid;
    int v = gid >> 6;
    if (v >= NN) return;
    int lane = tid & 63;
    int li = lane & 15;      // col group: cols [li*8, li*8+8)
    int eg = lane >> 4;      // edge slot 0..3
    int cb = li * 8;
    float scv[8], shv[8];
    if (APPLY_BN) {
        float4 s0 = *(const float4*)(scsh + cb);
        float4 s1 = *(const float4*)(scsh + cb + 4);
        float4 t0 = *(const float4*)(scsh + EMB + cb);
        float4 t1 = *(const float4*)(scsh + EMB + cb + 4);
        scv[0]=s0.x; scv[1]=s0.y; scv[2]=s0.z; scv[3]=s0.w;
        scv[4]=s1.x; scv[5]=s1.y; scv[6]=s1.z; scv[7]=s1.w;
        shv[0]=t0.x; shv[1]=t0.y; shv[2]=t0.z; shv[3]=t0.w;
        shv[4]=t1.x; shv[5]=t1.y; shv[6]=t1.z; shv[7]=t1.w;
    }
    float acc[8] = {0.f,0.f,0.f,0.f,0.f,0.f,0.f,0.f};
    auto accum8 = [&](uint4 u) {
        float2 p0 = uph2(u.x), p1 = uph2(u.y), p2 = uph2(u.z), p3 = uph2(u.w);
        float t[8] = {p0.x, p0.y, p1.x, p1.y, p2.x, p2.y, p3.x, p3.y};
        #pragma unroll
        for (int j = 0; j < 8; ++j) {
            float xx = t[j];
            if (APPLY_BN) {
                xx = xx * scv[j] + shv[j];
                xx = (xx > 0.f) ? xx : (__expf(xx) - 1.f);
            }
            acc[j] += xx;
        }
    };
    int e0 = row_start[v], e1 = row_start[v + 1];
    int e = e0;
    for (; e + 16 <= e1; e += 16) {
        int sA = sorted_srcc[e + eg];
        int sB = sorted_srcc[e + 4 + eg];
        int sC = sorted_srcc[e + 8 + eg];
        int sD = sorted_srcc[e + 12 + eg];
        uint4 uA = *(const uint4*)(st16 + (size_t)sA * EMB + cb);
        uint4 uB = *(const uint4*)(st16 + (size_t)sB * EMB + cb);
        uint4 uC = *(const uint4*)(st16 + (size_t)sC * EMB + cb);
        uint4 uD = *(const uint4*)(st16 + (size_t)sD * EMB + cb);
        accum8(uA); accum8(uB); accum8(uC); accum8(uD);
    }
    // pipelined tail: up to 15 edges, all guarded gathers issued independently
    if (e < e1) {
        int i0 = e + eg, i1 = e + 4 + eg, i2 = e + 8 + eg, i3 = e + 12 + eg;
        bool g0 = (i0 < e1), g1 = (i1 < e1), g2 = (i2 < e1), g3 = (i3 < e1);
        uint4 u0, u1, u2, u3;
        if (g0) { int s = sorted_srcc[i0]; u0 = *(const uint4*)(st16 + (size_t)s * EMB + cb); }
        if (g1) { int s = sorted_srcc[i1]; u1 = *(const uint4*)(st16 + (size_t)s * EMB + cb); }
        if (g2) { int s = sorted_srcc[i2]; u2 = *(const uint4*)(st16 + (size_t)s * EMB + cb); }
        if (g3) { int s = sorted_srcc[i3]; u3 = *(const uint4*)(st16 + (size_t)s * EMB + cb); }
        if (g0) accum8(u0);
        if (g1) accum8(u1);
        if (g2) accum8(u2);
        if (g3) accum8(u3);
    }
    // fold the 4 edge slots (lane^16, lane^32)
    #pragma unroll
    for (int j = 0; j < 8; ++j) {
        acc[j] += __shfl_xor(acc[j], 16, 64);
        acc[j] += __shfl_xor(acc[j], 32, 64);
    }
    // epilogue: self + (deg+1)*bs + attsum@W_e  (redundant across eg groups)
    float deg = (float)(e1 - e0);
    const float* at = attsum + (size_t)v * 8;
    float4 a03 = *(const float4*)(at);
    float a4 = at[4];
    uint4 su = *(const uint4*)(st16 + (size_t)v * EMB + cb);
    float2 q0 = uph2(su.x), q1 = uph2(su.y), q2 = uph2(su.z), q3 = uph2(su.w);
    float sf[8] = {q0.x, q0.y, q1.x, q1.y, q2.x, q2.y, q3.x, q3.y};
    if (APPLY_BN) {
        #pragma unroll
        for (int j = 0; j < 8; ++j) {
            float xx = sf[j] * scv[j] + shv[j];
            sf[j] = (xx > 0.f) ? xx : (__expf(xx) - 1.f);
        }
    }
    float out[8];
    #pragma unroll
    for (int half = 0; half < 2; ++half) {
        int cbh = cb + half * 4;
        float4 bsv = *(const float4*)(bsum_e_l + cbh);
        float4 w0 = *(const float4*)(W_e_l + 0 * EMB + cbh);
        float4 w1 = *(const float4*)(W_e_l + 1 * EMB + cbh);
        float4 w2 = *(const float4*)(W_e_l + 2 * EMB + cbh);
        float4 w3 = *(const float4*)(W_e_l + 3 * EMB + cbh);
        float4 w4 = *(const float4*)(W_e_l + 4 * EMB + cbh);
        const float* bsp = (const float*)&bsv;
        const float* w0p = (const float*)&w0;
        const float* w1p = (const float*)&w1;
        const float* w2p = (const float*)&w2;
        const float* w3p = (const float*)&w3;
        const float* w4p = (const float*)&w4;
        #pragma unroll
        for (int j = 0; j < 4; ++j) {
            int jj = half * 4 + j;
            out[jj] = acc[jj] + sf[jj] + (deg + 1.f) * bsp[j]
                    + a03.x * w0p[j] + a03.y * w1p[j] + a03.z * w2p[j]
                    + a03.w * w3p[j] + a4 * w4p[j];
        }
    }
    if (eg == 0) {
        uint4 hi, lo;
        split2(out[0], out[1], hi.x, lo.x);
        split2(out[2], out[3], hi.y, lo.y);
        split2(out[4], out[5], hi.z, lo.z);
        split2(out[6], out[7], hi.w, lo.w);
        *(uint4*)(agg_hi + (size_t)v * 64 + li * 4) = hi;
        *(uint4*)(agg_lo + (size_t)v * 64 + li * 4) = lo;
    }
}

// ---------------------------------------------------------------------------
// k_mlp (MFMA, hi/lo split = fp32-accurate), fragment-packed weights.
// 32-row tile, 4 waves. D-frag: col=lane&15 (node), row=quad*4+reg.
// Writes z as fp16. BN stats -> replicated buffers (blockIdx&31).
// ---------------------------------------------------------------------------
__global__ __launch_bounds__(256) void k_mlp(
        const unsigned short* __restrict__ aggh, const unsigned short* __restrict__ aggl,
        const unsigned short* __restrict__ W1ph, const unsigned short* __restrict__ W1pl,
        const float* __restrict__ b1_l,
        const unsigned short* __restrict__ W2ph, const unsigned short* __restrict__ W2pl,
        const float* __restrict__ b2_l,
        unsigned short* __restrict__ z16, float* __restrict__ stats) {
    __shared__ unsigned short Ahi[32][136];   // 8.5 KB  (+8 pad)
    __shared__ unsigned short Alo[32][136];   // 8.5 KB
    __shared__ unsigned short Hhi[32][264];   // 16.5 KB (+8 pad)
    __shared__ unsigned short Hlo[32][264];   // 16.5 KB
    int tid = threadIdx.x;
    int r0 = blockIdx.x * 32;
    int rep = blockIdx.x & (NREP - 1);
    // stage A hi/lo tiles (zero-pad rows >= NN)
    #pragma unroll
    for (int it = 0; it < 4; ++it) {
        int idx = it * 256 + tid;       // 0..1023
        int plane = idx >> 9;
        int k = idx & 511;
        int row = k >> 4;
        int cb = (k & 15) * 8;
        int grow = r0 + row;
        uint4 val = make_uint4(0u, 0u, 0u, 0u);
        const unsigned short* srcp = plane ? aggl : aggh;
        if (grow < NN) val = *(const uint4*)(srcp + (size_t)grow * EMB + cb);
        if (plane) *(uint4*)(&Alo[row][cb]) = val;
        else       *(uint4*)(&Ahi[row][cb]) = val;
    }
    __syncthreads();
    int wave = tid >> 6, lane = tid & 63;
    int l16 = lane & 15, quad = lane >> 4;
    // ---- phase 1: wave owns hid cols [64*wave, 64*wave+64)
    {
        bf16x8 ahi[2][4], alo[2][4];
        #pragma unroll
        for (int nt = 0; nt < 2; ++nt)
            #pragma unroll
            for (int kk = 0; kk < 4; ++kk) {
                ahi[nt][kk] = *(const bf16x8*)(&Ahi[nt * 16 + l16][kk * 32 + quad * 8]);
                alo[nt][kk] = *(const bf16x8*)(&Alo[nt * 16 + l16][kk * 32 + quad * 8]);
            }
        #pragma unroll
        for (int h2 = 0; h2 < 4; ++h2) {
            bf16x8 whi[4], wlo[4];
            #pragma unroll
            for (int kk = 0; kk < 4; ++kk) {
                size_t off = ((((size_t)(wave * 4 + h2) * 4) + kk) * 64 + lane) * 8;
                whi[kk] = *(const bf16x8*)(W1ph + off);
                wlo[kk] = *(const bf16x8*)(W1pl + off);
            }
            float4 bv = *(const float4*)(b1_l + wave * 64 + h2 * 16 + quad * 4);
            f32x4 bias = {bv.x, bv.y, bv.z, bv.w};
            #pragma unroll
            for (int nt = 0; nt < 2; ++nt) {
                f32x4 acc = bias;
                #pragma unroll
                for (int kk = 0; kk < 4; ++kk)
                    acc = __builtin_amdgcn_mfma_f32_16x16x32_bf16(whi[kk], ahi[nt][kk], acc, 0, 0, 0);
                #pragma unroll
                for (int kk = 0; kk < 4; ++kk)
                    acc = __builtin_amdgcn_mfma_f32_16x16x32_bf16(whi[kk], alo[nt][kk], acc, 0, 0, 0);
                #pragma unroll
                for (int kk = 0; kk < 4; ++kk)
                    acc = __builtin_amdgcn_mfma_f32_16x16x32_bf16(wlo[kk], ahi[nt][kk], acc, 0, 0, 0);
                float v0 = fmaxf(acc[0], 0.f), v1 = fmaxf(acc[1], 0.f);
                float v2 = fmaxf(acc[2], 0.f), v3 = fmaxf(acc[3], 0.f);
                unsigned hiA, loA, hiB, loB;
                split2(v0, v1, hiA, loA);
                split2(v2, v3, hiB, loB);
                int col = wave * 64 + h2 * 16 + quad * 4;
                *(uint2*)(&Hhi[nt * 16 + l16][col]) = make_uint2(hiA, hiB);
                *(uint2*)(&Hlo[nt * 16 + l16][col]) = make_uint2(loA, loB);
            }
        }
    }
    __syncthreads();
    // ---- phase 2: wave owns out cols [32*wave, 32*wave+32)
    float ss[2][4] = {}, sq[2][4] = {};
    #pragma unroll
    for (int o2 = 0; o2 < 2; ++o2) {
        bf16x8 w2h[8], w2l[8];
        #pragma unroll
        for (int kk = 0; kk < 8; ++kk) {
            size_t off = ((((size_t)(wave * 2 + o2) * 8) + kk) * 64 + lane) * 8;
            w2h[kk] = *(const bf16x8*)(W2ph + off);
            w2l[kk] = *(const bf16x8*)(W2pl + off);
        }
        float4 bv = *(const float4*)(b2_l + wave * 32 + o2 * 16 + quad * 4);
        f32x4 bias = {bv.x, bv.y, bv.z, bv.w};
        #pragma unroll
        for (int nt = 0; nt < 2; ++nt) {
            bf16x8 hh[8], hl[8];
            #pragma unroll
            for (int kk = 0; kk < 8; ++kk) {
                hh[kk] = *(const bf16x8*)(&Hhi[nt * 16 + l16][kk * 32 + quad * 8]);
                hl[kk] = *(const bf16x8*)(&Hlo[nt * 16 + l16][kk * 32 + quad * 8]);
            }
            f32x4 acc = bias;
            #pragma unroll
            for (int kk = 0; kk < 8; ++kk)
                acc = __builtin_amdgcn_mfma_f32_16x16x32_bf16(w2h[kk], hh[kk], acc, 0, 0, 0);
            #pragma unroll
            for (int kk = 0; kk < 8; ++kk)
                acc = __builtin_amdgcn_mfma_f32_16x16x32_bf16(w2h[kk], hl[kk], acc, 0, 0, 0);
            #pragma unroll
            for (int kk = 0; kk < 8; ++kk)
                acc = __builtin_amdgcn_mfma_f32_16x16x32_bf16(w2l[kk], hh[kk], acc, 0, 0, 0);
            int node = r0 + nt * 16 + l16;
            if (node < NN) {
                uint2 p = make_uint2(pkh2(acc[0], acc[1]), pkh2(acc[2], acc[3]));
                *(uint2*)(z16 + (size_t)node * EMB + wave * 32 + o2 * 16 + quad * 4) = p;
                #pragma unroll
                for (int r = 0; r < 4; ++r) {
                    ss[o2][r] += acc[r];
                    sq[o2][r] += acc[r] * acc[r];
                }
            }
        }
    }
    #pragma unroll
    for (int o2 = 0; o2 < 2; ++o2)
        #pragma unroll
        for (int r = 0; r < 4; ++r) {
            float s = ss[o2][r], q = sq[o2][r];
            #pragma unroll
            for (int m = 1; m < 16; m <<= 1) {
                s += __shfl_xor(s, m, 64);
                q += __shfl_xor(q, m, 64);
            }
            if (l16 == 0) {
                int oc = wave * 32 + o2 * 16 + quad * 4 + r;
                atomicAdd(&stats[rep * 2 * EMB + oc], s);
                atomicAdd(&stats[rep * 2 * EMB + EMB + oc], q);
            }
        }
}

// ---------------------------------------------------------------------------
// k_bnscale: ONE block reduces the NREP stats replicas -> sc/sh (1 KB).
// (Next layer's k_agg re-zeroes the replicas.)
// ---------------------------------------------------------------------------
__global__ void k_bnscale(const float* __restrict__ stats,
                          const float* __restrict__ gamma_l, const float* __restrict__ beta_l,
                          float* __restrict__ scsh) {
    int tid = threadIdx.x;  // 128 threads
    float s = 0.f, q = 0.f;
    #pragma unroll
    for (int r = 0; r < NREP; ++r) {
        s += stats[r * 2 * EMB + tid];
        q += stats[r * 2 * EMB + EMB + tid];
    }
    float mu = s * (1.f / NN);
    float var = q * (1.f / NN) - mu * mu;
    float sf = gamma_l[tid] * rsqrtf(var + BN_EPS);
    scsh[tid] = sf;
    scsh[EMB + tid] = beta_l[tid] - mu * sf;
}

// ---------------------------------------------------------------------------
// k_bn (final layer only): z16 -> fp32 z*sc + sh into d_out.
// ---------------------------------------------------------------------------
__global__ void k_bn(const unsigned short* __restrict__ z16, const float* __restrict__ scsh,
                     float* __restrict__ fout) {
    __shared__ float sc[EMB], sh[EMB];
    int tid = threadIdx.x;
    if (tid < EMB) {
        sc[tid] = scsh[tid];
        sh[tid] = scsh[EMB + tid];
    }
    __syncthreads();
    int gid = blockIdx.x * blockDim.x + tid;
    if (gid >= NN * EMB / 4) return;
    int c = (gid & 31) << 2;
    uint2 zp = *(const uint2*)(z16 + (size_t)gid * 4);
    float2 z01 = uph2(zp.x), z23 = uph2(zp.y);
    float o0 = z01.x * sc[c + 0] + sh[c + 0];
    float o1 = z01.y * sc[c + 1] + sh[c + 1];
    float o2 = z23.x * sc[c + 2] + sh[c + 2];
    float o3 = z23.y * sc[c + 3] + sh[c + 3];
    *(float4*)(fout + (size_t)gid * 4) = make_float4(o0, o1, o2, o3);
}

// ---------------------------------------------------------------------------
extern "C" void kernel_launch(void* const* d_in, const int* in_sizes, int n_in,
                              void* d_out, int out_size, void* d_ws, size_t ws_size,
                              hipStream_t stream) {
    const float* x         = (const float*)d_in[0];
    const float* edge_attr = (const float*)d_in[1];
    const int*   edge_idx  = (const int*)d_in[2];
    const float* W_x   = (const float*)d_in[3];
    const float* b_x   = (const float*)d_in[4];
    const float* W_e   = (const float*)d_in[5];
    const float* b_e   = (const float*)d_in[6];
    const float* W1    = (const float*)d_in[7];
    const float* b1    = (const float*)d_in[8];
    const float* W2    = (const float*)d_in[9];
    const float* b2    = (const float*)d_in[10];
    const float* gamma = (const float*)d_in[11];
    const float* beta  = (const float*)d_in[12];
    float* fout = (float*)d_out;  // final BN writes fp32 here

    const int* src = edge_idx;
    const int* dst = edge_idx + NE;

    char* p = (char*)d_ws;
    auto alloc = [&](size_t bytes) { char* q = p; p += (bytes + 255) & ~(size_t)255; return q; };
    unsigned short* h16 = (unsigned short*)alloc((size_t)NN * EMB * 2);
    unsigned short* z16 = (unsigned short*)alloc((size_t)NN * EMB * 2);
    unsigned* agg_hi = (unsigned*)alloc((size_t)NN * EMB * 2);
    unsigned* agg_lo = (unsigned*)alloc((size_t)NN * EMB * 2);
    unsigned short* W1ph = (unsigned short*)alloc((size_t)NL * HID * EMB * 2);
    unsigned short* W1pl = (unsigned short*)alloc((size_t)NL * HID * EMB * 2);
    unsigned short* W2ph = (unsigned short*)alloc((size_t)NL * EMB * HID * 2);
    unsigned short* W2pl = (unsigned short*)alloc((size_t)NL * EMB * HID * 2);
    int*   row_start  = (int*)alloc((NN + 1) * sizeof(int));
    int*   counts     = (int*)alloc(NN * sizeof(int));
    int*   cursor     = (int*)alloc(NN * sizeof(int));
    uint4* sorted_pk  = (uint4*)alloc((size_t)NE * sizeof(uint4));
    int*   sorted_srcc= (int*)alloc((size_t)NE * sizeof(int));
    float* attsum     = (float*)alloc((size_t)NN * 8 * sizeof(float));
    int*   bsum       = (int*)alloc(SCAN_B * sizeof(int));
    int*   bpre       = (int*)alloc(SCAN_B * sizeof(int));
    float* stats      = (float*)alloc((size_t)NREP * 2 * EMB * sizeof(float));
    float* scsh       = (float*)alloc(2 * EMB * sizeof(float));
    float* bsum_x     = (float*)alloc(EMB * sizeof(float));
    float* bsum_e     = (float*)alloc(NL * EMB * sizeof(float));

    k_prep<<<256, 256, 0, stream>>>(b_x, b_e, bsum_x, bsum_e, counts, cursor);
    k_prepw<<<(2 * NL * EMB * HID + 255) / 256, 256, 0, stream>>>(W1, W2, W1ph, W1pl, W2ph, W2pl);
    k_init<<<(NN * 32 + 255) / 256, 256, 0, stream>>>(x, W_x, bsum_x, h16);
    k_hist<<<(NE + 255) / 256, 256, 0, stream>>>(dst, counts);
    k_scan1<<<SCAN_B, 256, 0, stream>>>(counts, bsum);
    k_scan2<<<1, 256, 0, stream>>>(bsum, bpre, row_start);
    k_scan3<<<SCAN_B, 256, 0, stream>>>(counts, bpre, row_start);
    k_fill<<<(NE + 255) / 256, 256, 0, stream>>>(src, dst, edge_attr, row_start, cursor,
                                                 sorted_pk);
    k_esum<<<SCAN_B, 256, 0, stream>>>(sorted_pk, row_start, attsum, sorted_srcc);
    const int AGG_GRID = (NN * 64 + 255) / 256;
    for (int l = 0; l < NL; ++l) {
        if (l == 0) {
            k_agg<0><<<AGG_GRID, 256, 0, stream>>>(
                h16, sorted_srcc, attsum, scsh,
                W_e + (size_t)l * EF * EMB, bsum_e + l * EMB, row_start,
                agg_hi, agg_lo, stats);
        } else {
            k_agg<1><<<AGG_GRID, 256, 0, stream>>>(
                z16, sorted_srcc, attsum, scsh,
                W_e + (size_t)l * EF * EMB, bsum_e + l * EMB, row_start,
                agg_hi, agg_lo, stats);
        }
        k_mlp<<<(NN + 31) / 32, 256, 0, stream>>>(
            (const unsigned short*)agg_hi, (const unsigned short*)agg_lo,
            W1ph + (size_t)l * HID * EMB, W1pl + (size_t)l * HID * EMB, b1 + (size_t)l * HID,
            W2ph + (size_t)l * EMB * HID, W2pl + (size_t)l * EMB * HID, b2 + (size_t)l * EMB,
            z16, stats);
        k_bnscale<<<1, 128, 0, stream>>>(stats, gamma + l * EMB, beta + l * EMB, scsh);
    }
    k_bn<<<(NN * EMB / 4 + 255) / 256, 256, 0, stream>>>(z16, scsh, fout);
}

// Round 13
// 617.696 us; speedup vs baseline: 1.3905x; 1.0784x over previous
//
#include <hip/hip_runtime.h>
#include <math.h>

#define NN 50000
#define NE 800000
#define EMB 128
#define HID 256
#define NF 7
#define EF 5
#define NL 5
#define BN_EPS 1e-5f
#define NREP 32     // stats replicas to kill same-line atomic serialization
#define SCAN_B 196  // ceil(NN/256)

typedef _Float16 f16x8 __attribute__((ext_vector_type(8)));
typedef __attribute__((ext_vector_type(4))) float f32x4;

// fp16 pack/unpack
__device__ inline unsigned pkh2(float a, float b) {
    union { unsigned v; _Float16 h[2]; } x;
    x.h[0] = (_Float16)a; x.h[1] = (_Float16)b;
    return x.v;
}
__device__ inline float2 uph2(unsigned u) {
    union { unsigned v; _Float16 h[2]; } x; x.v = u;
    return make_float2((float)x.h[0], (float)x.h[1]);
}
__device__ inline unsigned short f2h_bits(float f) {
    _Float16 h = (_Float16)f;
    return __builtin_bit_cast(unsigned short, h);
}
__device__ inline float h_bits2f(unsigned short b) {
    return (float)__builtin_bit_cast(_Float16, b);
}

// ---------------------------------------------------------------------------
// k_prep: block 0 computes bias-sum vectors; all blocks zero CSR counts/cursor
// ---------------------------------------------------------------------------
__global__ void k_prep(const float* __restrict__ b_x, const float* __restrict__ b_e,
                       float* __restrict__ bsum_x, float* __restrict__ bsum_e,
                       int* __restrict__ counts, int* __restrict__ cursor) {
    int tid = threadIdx.x;
    if (blockIdx.x == 0 && tid < EMB) {
        float s = 0.f;
        for (int f = 0; f < NF; ++f) s += b_x[f * EMB + tid];
        bsum_x[tid] = s;
        for (int l = 0; l < NL; ++l) {
            float se = 0.f;
            for (int f = 0; f < EF; ++f) se += b_e[(l * EF + f) * EMB + tid];
            bsum_e[l * EMB + tid] = se;
        }
    }
    int gid = blockIdx.x * blockDim.x + tid;
    int stride = gridDim.x * blockDim.x;
    for (int i = gid; i < NN; i += stride) { counts[i] = 0; cursor[i] = 0; }
}

// ---------------------------------------------------------------------------
// k_prepw: fragment-pack + fp16 hi/lo split of weights (combined rel ~2^-22).
// W1p layout: [L][wave(4)][h2(4)][kk(4)][lane(64)][j(8)]  (lane-contiguous 16B)
// W2p layout: [L][wave(4)][o2(2)][kk(8)][lane(64)][j(8)]
// ---------------------------------------------------------------------------
__global__ void k_prepw(const float* __restrict__ W1, const float* __restrict__ W2,
                        unsigned short* __restrict__ W1ph, unsigned short* __restrict__ W1pl,
                        unsigned short* __restrict__ W2ph, unsigned short* __restrict__ W2pl) {
    const int TOT = NL * EMB * HID;   // 163840 per matrix
    int gid = blockIdx.x * blockDim.x + threadIdx.x;
    if (gid < TOT) {
        int l = gid / (EMB * HID);
        int r = gid % (EMB * HID);             // 32768
        int w = r >> 13;                       // /8192
        int rem = r & 8191;
        int h2 = rem >> 11;                    // /2048
        int rem2 = rem & 2047;
        int kk = rem2 >> 9;                    // /512
        int rem3 = rem2 & 511;
        int lane = rem3 >> 3;
        int j = rem3 & 7;
        int hc = w * 64 + h2 * 16 + (lane & 15);
        int k = kk * 32 + (lane >> 4) * 8 + j;
        float wv = W1[((size_t)l * EMB + k) * HID + hc];
        unsigned short hi = f2h_bits(wv);
        W1ph[gid] = hi;
        W1pl[gid] = f2h_bits(wv - h_bits2f(hi));
    } else if (gid < 2 * TOT) {
        int g = gid - TOT;
        int l = g / (EMB * HID);
        int r = g % (EMB * HID);
        int w = r >> 13;
        int rem = r & 8191;
        int o2 = rem >> 12;                    // /4096
        int rem2 = rem & 4095;
        int kk = rem2 >> 9;
        int rem3 = rem2 & 511;
        int lane = rem3 >> 3;
        int j = rem3 & 7;
        int oc = w * 32 + o2 * 16 + (lane & 15);
        int k2 = kk * 32 + (lane >> 4) * 8 + j;
        float wv = W2[((size_t)l * HID + k2) * EMB + oc];
        unsigned short hi = f2h_bits(wv);
        W2ph[g] = hi;
        W2pl[g] = f2h_bits(wv - h_bits2f(hi));
    }
}

// ---------------------------------------------------------------------------
// k_init: h(fp16) = x @ W_x + bsum_x  (32 threads/node, 4 cols each)
// ---------------------------------------------------------------------------
__global__ void k_init(const float* __restrict__ x, const float* __restrict__ W_x,
                       const float* __restrict__ bsum_x, unsigned short* __restrict__ h16) {
    int gid = blockIdx.x * blockDim.x + threadIdx.x;
    int v = gid >> 5;
    if (v >= NN) return;
    int c = (gid & 31) << 2;
    float4 acc = *(const float4*)(bsum_x + c);
    #pragma unroll
    for (int f = 0; f < NF; ++f) {
        float xv = x[(size_t)v * NF + f];
        float4 w = *(const float4*)(W_x + f * EMB + c);
        acc.x += xv * w.x; acc.y += xv * w.y; acc.z += xv * w.z; acc.w += xv * w.w;
    }
    uint2 p = make_uint2(pkh2(acc.x, acc.y), pkh2(acc.z, acc.w));
    *(uint2*)(h16 + (size_t)v * EMB + c) = p;
}

// ---------------------------------------------------------------------------
// CSR build: histogram of dst, 3-phase multi-block scan, packed bucket fill
// ---------------------------------------------------------------------------
__global__ void k_hist(const int* __restrict__ dst, int* __restrict__ counts) {
    int e = blockIdx.x * blockDim.x + threadIdx.x;
    if (e < NE) atomicAdd(&counts[dst[e]], 1);
}

__global__ void k_scan1(const int* __restrict__ counts, int* __restrict__ bsum) {
    int tid = threadIdx.x;
    int i = blockIdx.x * 256 + tid;
    int v = (i < NN) ? counts[i] : 0;
    #pragma unroll
    for (int off = 1; off < 64; off <<= 1) v += __shfl_xor(v, off, 64);
    __shared__ int ws[4];
    if ((tid & 63) == 0) ws[tid >> 6] = v;
    __syncthreads();
    if (tid == 0) bsum[blockIdx.x] = ws[0] + ws[1] + ws[2] + ws[3];
}

__global__ void k_scan2(const int* __restrict__ bsum, int* __restrict__ bpre,
                        int* __restrict__ row_start) {
    int tid = threadIdx.x;  // 256 threads
    int x = (tid < SCAN_B) ? bsum[tid] : 0;
    int lane = tid & 63, wv = tid >> 6;
    int v = x;
    #pragma unroll
    for (int off = 1; off < 64; off <<= 1) {
        int t = __shfl_up(v, off, 64);
        if (lane >= off) v += t;
    }
    __shared__ int wsum[4];
    if (lane == 63) wsum[wv] = v;
    __syncthreads();
    int woff = 0;
    #pragma unroll
    for (int w = 0; w < 4; ++w) if (w < wv) woff += wsum[w];
    int incl = v + woff;
    if (tid < SCAN_B) bpre[tid] = incl - x;
    if (tid == 255) row_start[NN] = incl;
}

__global__ void k_scan3(const int* __restrict__ counts, const int* __restrict__ bpre,
                        int* __restrict__ row_start) {
    int tid = threadIdx.x;
    int i = blockIdx.x * 256 + tid;
    int x = (i < NN) ? counts[i] : 0;
    int lane = tid & 63, wv = tid >> 6;
    int v = x;
    #pragma unroll
    for (int off = 1; off < 64; off <<= 1) {
        int t = __shfl_up(v, off, 64);
        if (lane >= off) v += t;
    }
    __shared__ int wsum[4];
    if (lane == 63) wsum[wv] = v;
    __syncthreads();
    int woff = 0;
    #pragma unroll
    for (int w = 0; w < 4; ++w) if (w < wv) woff += wsum[w];
    if (i < NN) row_start[i] = bpre[blockIdx.x] + v + woff - x;
}

// k_fill: ONE 16-B scatter per edge: {src, fp16 ea0..ea4}  (known-good ~52us).
__global__ void k_fill(const int* __restrict__ src, const int* __restrict__ dst,
                       const float* __restrict__ edge_attr,
                       const int* __restrict__ row_start, int* __restrict__ cursor,
                       uint4* __restrict__ sorted_pk) {
    int e = blockIdx.x * blockDim.x + threadIdx.x;
    if (e >= NE) return;
    int d = dst[e];
    int pos = atomicAdd(&cursor[d], 1);
    int idx = row_start[d] + pos;
    const float* ea = edge_attr + (size_t)e * EF;
    float a0 = ea[0], a1 = ea[1], a2 = ea[2], a3 = ea[3], a4 = ea[4];
    uint4 pk;
    pk.x = (unsigned)src[e];
    pk.y = pkh2(a0, a1);
    pk.z = pkh2(a2, a3);
    pk.w = pkh2(a4, 0.f);
    sorted_pk[idx] = pk;
}

// ---------------------------------------------------------------------------
// k_esum (once): per node, sum incoming edge attrs -> attsum[v][8] =
// {a0..a4, deg, 0, 0}; emit compact sorted_srcc[e] (sequential write).
// ---------------------------------------------------------------------------
__global__ void k_esum(const uint4* __restrict__ sorted_pk,
                       const int* __restrict__ row_start,
                       float* __restrict__ attsum, int* __restrict__ sorted_srcc) {
    int v = blockIdx.x * blockDim.x + threadIdx.x;
    if (v >= NN) return;
    int e0 = row_start[v], e1 = row_start[v + 1];
    float s0 = 0.f, s1 = 0.f, s2 = 0.f, s3 = 0.f, s4 = 0.f;
    for (int e = e0; e < e1; ++e) {
        uint4 pk = sorted_pk[e];
        sorted_srcc[e] = (int)pk.x;
        float2 a01 = uph2(pk.y), a23 = uph2(pk.z), a4x = uph2(pk.w);
        s0 += a01.x; s1 += a01.y; s2 += a23.x; s3 += a23.y; s4 += a4x.x;
    }
    float* o = attsum + (size_t)v * 8;
    *(float4*)(o) = make_float4(s0, s1, s2, s3);
    *(float4*)(o + 4) = make_float4(s4, (float)(e1 - e0), 0.f, 0.f);
}

// ---------------------------------------------------------------------------
// k_agg<APPLY_BN> (round-10 form, verified 51.4us): one wave per node, 2
// cols/lane, unroll-8 with readfirstlane'd src (SGPR-base gathers).
// agg[v] = state(v) + (deg+1)*bs + attsum[v]@W_e + sum_e state(src);
// state(u) = APPLY_BN ? ELU(z16[u]*sc+sh) : h16[u].
// Output: SINGLE fp16 plane agg16 (k_mlp now uses f16 MFMA).
// Blocks 0..31 zero the BN-stats replicas for this layer.
// ---------------------------------------------------------------------------
template<int APPLY_BN>
__global__ __launch_bounds__(256) void k_agg(
        const unsigned short* __restrict__ st16, const int* __restrict__ sorted_srcc,
        const float* __restrict__ attsum, const float* __restrict__ scsh,
        const float* __restrict__ W_e_l, const float* __restrict__ bsum_e_l,
        const int* __restrict__ row_start,
        unsigned short* __restrict__ agg16, float* __restrict__ stats) {
    int tid = threadIdx.x;
    if (blockIdx.x < NREP) stats[blockIdx.x * 2 * EMB + tid] = 0.f;  // 256 == 2*EMB
    int gid = blockIdx.x * 256 + tid;
    int v = gid >> 6;
    if (v >= NN) return;
    int c = (gid & 63) << 1;
    float2 we0 = *(const float2*)(W_e_l + 0 * EMB + c);
    float2 we1 = *(const float2*)(W_e_l + 1 * EMB + c);
    float2 we2 = *(const float2*)(W_e_l + 2 * EMB + c);
    float2 we3 = *(const float2*)(W_e_l + 3 * EMB + c);
    float2 we4 = *(const float2*)(W_e_l + 4 * EMB + c);
    float2 bs = *(const float2*)(bsum_e_l + c);
    float2 sc2 = make_float2(0.f, 0.f), sh2 = make_float2(0.f, 0.f);
    if (APPLY_BN) {
        sc2 = *(const float2*)(scsh + c);
        sh2 = *(const float2*)(scsh + EMB + c);
    }
    auto state = [&](unsigned u) -> float2 {
        float2 t = uph2(u);
        if (APPLY_BN) {
            t.x = t.x * sc2.x + sh2.x;
            t.y = t.y * sc2.y + sh2.y;
            t.x = (t.x > 0.f) ? t.x : (__expf(t.x) - 1.f);
            t.y = (t.y > 0.f) ? t.y : (__expf(t.y) - 1.f);
        }
        return t;
    };
    float2 hv = state(*(const unsigned*)(st16 + (size_t)v * EMB + c));
    const float* at = attsum + (size_t)v * 8;
    float4 a03 = *(const float4*)(at);
    float2 a45 = *(const float2*)(at + 4);   // a4, deg
    float ax = hv.x + (a45.y + 1.f) * bs.x
             + a03.x*we0.x + a03.y*we1.x + a03.z*we2.x + a03.w*we3.x + a45.x*we4.x;
    float ay = hv.y + (a45.y + 1.f) * bs.y
             + a03.x*we0.y + a03.y*we1.y + a03.z*we2.y + a03.w*we3.y + a45.x*we4.y;
    int e0 = row_start[v], e1 = row_start[v + 1];
    int e = e0;
    for (; e + 8 <= e1; e += 8) {
        int s0 = __builtin_amdgcn_readfirstlane(sorted_srcc[e + 0]);
        int s1 = __builtin_amdgcn_readfirstlane(sorted_srcc[e + 1]);
        int s2 = __builtin_amdgcn_readfirstlane(sorted_srcc[e + 2]);
        int s3 = __builtin_amdgcn_readfirstlane(sorted_srcc[e + 3]);
        int s4 = __builtin_amdgcn_readfirstlane(sorted_srcc[e + 4]);
        int s5 = __builtin_amdgcn_readfirstlane(sorted_srcc[e + 5]);
        int s6 = __builtin_amdgcn_readfirstlane(sorted_srcc[e + 6]);
        int s7 = __builtin_amdgcn_readfirstlane(sorted_srcc[e + 7]);
        unsigned u0 = *(const unsigned*)(st16 + (size_t)s0 * EMB + c);
        unsigned u1 = *(const unsigned*)(st16 + (size_t)s1 * EMB + c);
        unsigned u2 = *(const unsigned*)(st16 + (size_t)s2 * EMB + c);
        unsigned u3 = *(const unsigned*)(st16 + (size_t)s3 * EMB + c);
        unsigned u4 = *(const unsigned*)(st16 + (size_t)s4 * EMB + c);
        unsigned u5 = *(const unsigned*)(st16 + (size_t)s5 * EMB + c);
        unsigned u6 = *(const unsigned*)(st16 + (size_t)s6 * EMB + c);
        unsigned u7 = *(const unsigned*)(st16 + (size_t)s7 * EMB + c);
        float2 h0 = state(u0), h1 = state(u1), h2 = state(u2), h3 = state(u3);
        float2 h4 = state(u4), h5 = state(u5), h6 = state(u6), h7 = state(u7);
        ax += ((h0.x + h1.x) + (h2.x + h3.x)) + ((h4.x + h5.x) + (h6.x + h7.x));
        ay += ((h0.y + h1.y) + (h2.y + h3.y)) + ((h4.y + h5.y) + (h6.y + h7.y));
    }
    for (; e < e1; ++e) {
        int s = __builtin_amdgcn_readfirstlane(sorted_srcc[e]);
        float2 hs = state(*(const unsigned*)(st16 + (size_t)s * EMB + c));
        ax += hs.x;
        ay += hs.y;
    }
    *(unsigned*)(agg16 + (size_t)v * EMB + c) = pkh2(ax, ay);
}

// ---------------------------------------------------------------------------
// k_mlp (f16 MFMA): activations single fp16 plane, weights fp16 hi/lo
// (combined rel ~2^-22 -> effectively exact weights). 2-term MFMA both
// phases: 128 MFMA/wave vs 192. LDS 25 KB (was 51) -> ~5-6 blocks/CU.
// 32-row tile, 4 waves. D-frag: col=lane&15 (node), row=quad*4+reg.
// Writes z fp16; BN stats -> replicated buffers (blockIdx&31).
// ---------------------------------------------------------------------------
__global__ __launch_bounds__(256) void k_mlp(
        const unsigned short* __restrict__ agg16,
        const unsigned short* __restrict__ W1ph, const unsigned short* __restrict__ W1pl,
        const float* __restrict__ b1_l,
        const unsigned short* __restrict__ W2ph, const unsigned short* __restrict__ W2pl,
        const float* __restrict__ b2_l,
        unsigned short* __restrict__ z16, float* __restrict__ stats) {
    __shared__ unsigned short A16[32][136];    // 8.5 KB  (+8 pad)
    __shared__ unsigned short Hid16[32][264];  // 16.5 KB (+8 pad)
    int tid = threadIdx.x;
    int r0 = blockIdx.x * 32;
    int rep = blockIdx.x & (NREP - 1);
    // stage A tile (zero-pad rows >= NN): 512 lane-16B loads = 2 iterations
    #pragma unroll
    for (int it = 0; it < 2; ++it) {
        int idx = it * 256 + tid;       // 0..511
        int row = idx >> 4;
        int cb = (idx & 15) * 8;
        int grow = r0 + row;
        uint4 val = make_uint4(0u, 0u, 0u, 0u);
        if (grow < NN) val = *(const uint4*)(agg16 + (size_t)grow * EMB + cb);
        *(uint4*)(&A16[row][cb]) = val;
    }
    __syncthreads();
    int wave = tid >> 6, lane = tid & 63;
    int l16 = lane & 15, quad = lane >> 4;
    // ---- phase 1: wave owns hid cols [64*wave, 64*wave+64)
    {
        f16x8 af[2][4];
        #pragma unroll
        for (int nt = 0; nt < 2; ++nt)
            #pragma unroll
            for (int kk = 0; kk < 4; ++kk)
                af[nt][kk] = *(const f16x8*)(&A16[nt * 16 + l16][kk * 32 + quad * 8]);
        #pragma unroll
        for (int h2 = 0; h2 < 4; ++h2) {
            f16x8 whf[4], wlf[4];
            #pragma unroll
            for (int kk = 0; kk < 4; ++kk) {
                size_t off = ((((size_t)(wave * 4 + h2) * 4) + kk) * 64 + lane) * 8;
                whf[kk] = *(const f16x8*)(W1ph + off);
                wlf[kk] = *(const f16x8*)(W1pl + off);
            }
            float4 bv = *(const float4*)(b1_l + wave * 64 + h2 * 16 + quad * 4);
            f32x4 bias = {bv.x, bv.y, bv.z, bv.w};
            #pragma unroll
            for (int nt = 0; nt < 2; ++nt) {
                f32x4 acc = bias;
                #pragma unroll
                for (int kk = 0; kk < 4; ++kk)
                    acc = __builtin_amdgcn_mfma_f32_16x16x32_f16(whf[kk], af[nt][kk], acc, 0, 0, 0);
                #pragma unroll
                for (int kk = 0; kk < 4; ++kk)
                    acc = __builtin_amdgcn_mfma_f32_16x16x32_f16(wlf[kk], af[nt][kk], acc, 0, 0, 0);
                uint2 p;
                p.x = pkh2(fmaxf(acc[0], 0.f), fmaxf(acc[1], 0.f));
                p.y = pkh2(fmaxf(acc[2], 0.f), fmaxf(acc[3], 0.f));
                int col = wave * 64 + h2 * 16 + quad * 4;
                *(uint2*)(&Hid16[nt * 16 + l16][col]) = p;
            }
        }
    }
    __syncthreads();
    // ---- phase 2: wave owns out cols [32*wave, 32*wave+32)
    float ss[2][4] = {}, sq[2][4] = {};
    #pragma unroll
    for (int o2 = 0; o2 < 2; ++o2) {
        f16x8 w2h[8], w2l[8];
        #pragma unroll
        for (int kk = 0; kk < 8; ++kk) {
            size_t off = ((((size_t)(wave * 2 + o2) * 8) + kk) * 64 + lane) * 8;
            w2h[kk] = *(const f16x8*)(W2ph + off);
            w2l[kk] = *(const f16x8*)(W2pl + off);
        }
        float4 bv = *(const float4*)(b2_l + wave * 32 + o2 * 16 + quad * 4);
        f32x4 bias = {bv.x, bv.y, bv.z, bv.w};
        #pragma unroll
        for (int nt = 0; nt < 2; ++nt) {
            f16x8 hf[8];
            #pragma unroll
            for (int kk = 0; kk < 8; ++kk)
                hf[kk] = *(const f16x8*)(&Hid16[nt * 16 + l16][kk * 32 + quad * 8]);
            f32x4 acc = bias;
            #pragma unroll
            for (int kk = 0; kk < 8; ++kk)
                acc = __builtin_amdgcn_mfma_f32_16x16x32_f16(w2h[kk], hf[kk], acc, 0, 0, 0);
            #pragma unroll
            for (int kk = 0; kk < 8; ++kk)
                acc = __builtin_amdgcn_mfma_f32_16x16x32_f16(w2l[kk], hf[kk], acc, 0, 0, 0);
            int node = r0 + nt * 16 + l16;
            if (node < NN) {
                uint2 p = make_uint2(pkh2(acc[0], acc[1]), pkh2(acc[2], acc[3]));
                *(uint2*)(z16 + (size_t)node * EMB + wave * 32 + o2 * 16 + quad * 4) = p;
                #pragma unroll
                for (int r = 0; r < 4; ++r) {
                    ss[o2][r] += acc[r];
                    sq[o2][r] += acc[r] * acc[r];
                }
            }
        }
    }
    #pragma unroll
    for (int o2 = 0; o2 < 2; ++o2)
        #pragma unroll
        for (int r = 0; r < 4; ++r) {
            float s = ss[o2][r], q = sq[o2][r];
            #pragma unroll
            for (int m = 1; m < 16; m <<= 1) {
                s += __shfl_xor(s, m, 64);
                q += __shfl_xor(q, m, 64);
            }
            if (l16 == 0) {
                int oc = wave * 32 + o2 * 16 + quad * 4 + r;
                atomicAdd(&stats[rep * 2 * EMB + oc], s);
                atomicAdd(&stats[rep * 2 * EMB + EMB + oc], q);
            }
        }
}

// ---------------------------------------------------------------------------
// k_bnscale: ONE block reduces the NREP stats replicas -> sc/sh (1 KB).
// (Next layer's k_agg re-zeroes the replicas.)
// ---------------------------------------------------------------------------
__global__ void k_bnscale(const float* __restrict__ stats,
                          const float* __restrict__ gamma_l, const float* __restrict__ beta_l,
                          float* __restrict__ scsh) {
    int tid = threadIdx.x;  // 128 threads
    float s = 0.f, q = 0.f;
    #pragma unroll
    for (int r = 0; r < NREP; ++r) {
        s += stats[r * 2 * EMB + tid];
        q += stats[r * 2 * EMB + EMB + tid];
    }
    float mu = s * (1.f / NN);
    float var = q * (1.f / NN) - mu * mu;
    float sf = gamma_l[tid] * rsqrtf(var + BN_EPS);
    scsh[tid] = sf;
    scsh[EMB + tid] = beta_l[tid] - mu * sf;
}

// ---------------------------------------------------------------------------
// k_bn (final layer only): z16 -> fp32 z*sc + sh into d_out.
// ---------------------------------------------------------------------------
__global__ void k_bn(const unsigned short* __restrict__ z16, const float* __restrict__ scsh,
                     float* __restrict__ fout) {
    __shared__ float sc[EMB], sh[EMB];
    int tid = threadIdx.x;
    if (tid < EMB) {
        sc[tid] = scsh[tid];
        sh[tid] = scsh[EMB + tid];
    }
    __syncthreads();
    int gid = blockIdx.x * blockDim.x + tid;
    if (gid >= NN * EMB / 4) return;
    int c = (gid & 31) << 2;
    uint2 zp = *(const uint2*)(z16 + (size_t)gid * 4);
    float2 z01 = uph2(zp.x), z23 = uph2(zp.y);
    float o0 = z01.x * sc[c + 0] + sh[c + 0];
    float o1 = z01.y * sc[c + 1] + sh[c + 1];
    float o2 = z23.x * sc[c + 2] + sh[c + 2];
    float o3 = z23.y * sc[c + 3] + sh[c + 3];
    *(float4*)(fout + (size_t)gid * 4) = make_float4(o0, o1, o2, o3);
}

// ---------------------------------------------------------------------------
extern "C" void kernel_launch(void* const* d_in, const int* in_sizes, int n_in,
                              void* d_out, int out_size, void* d_ws, size_t ws_size,
                              hipStream_t stream) {
    const float* x         = (const float*)d_in[0];
    const float* edge_attr = (const float*)d_in[1];
    const int*   edge_idx  = (const int*)d_in[2];
    const float* W_x   = (const float*)d_in[3];
    const float* b_x   = (const float*)d_in[4];
    const float* W_e   = (const float*)d_in[5];
    const float* b_e   = (const float*)d_in[6];
    const float* W1    = (const float*)d_in[7];
    const float* b1    = (const float*)d_in[8];
    const float* W2    = (const float*)d_in[9];
    const float* b2    = (const float*)d_in[10];
    const float* gamma = (const float*)d_in[11];
    const float* beta  = (const float*)d_in[12];
    float* fout = (float*)d_out;  // final BN writes fp32 here

    const int* src = edge_idx;
    const int* dst = edge_idx + NE;

    char* p = (char*)d_ws;
    auto alloc = [&](size_t bytes) { char* q = p; p += (bytes + 255) & ~(size_t)255; return q; };
    unsigned short* h16  = (unsigned short*)alloc((size_t)NN * EMB * 2);
    unsigned short* z16  = (unsigned short*)alloc((size_t)NN * EMB * 2);
    unsigned short* agg16 = (unsigned short*)alloc((size_t)NN * EMB * 2);
    unsigned short* W1ph = (unsigned short*)alloc((size_t)NL * HID * EMB * 2);
    unsigned short* W1pl = (unsigned short*)alloc((size_t)NL * HID * EMB * 2);
    unsigned short* W2ph = (unsigned short*)alloc((size_t)NL * EMB * HID * 2);
    unsigned short* W2pl = (unsigned short*)alloc((size_t)NL * EMB * HID * 2);
    int*   row_start  = (int*)alloc((NN + 1) * sizeof(int));
    int*   counts     = (int*)alloc(NN * sizeof(int));
    int*   cursor     = (int*)alloc(NN * sizeof(int));
    uint4* sorted_pk  = (uint4*)alloc((size_t)NE * sizeof(uint4));
    int*   sorted_srcc= (int*)alloc((size_t)NE * sizeof(int));
    float* attsum     = (float*)alloc((size_t)NN * 8 * sizeof(float));
    int*   bsum       = (int*)alloc(SCAN_B * sizeof(int));
    int*   bpre       = (int*)alloc(SCAN_B * sizeof(int));
    float* stats      = (float*)alloc((size_t)NREP * 2 * EMB * sizeof(float));
    float* scsh       = (float*)alloc(2 * EMB * sizeof(float));
    float* bsum_x     = (float*)alloc(EMB * sizeof(float));
    float* bsum_e     = (float*)alloc(NL * EMB * sizeof(float));

    k_prep<<<256, 256, 0, stream>>>(b_x, b_e, bsum_x, bsum_e, counts, cursor);
    k_prepw<<<(2 * NL * EMB * HID + 255) / 256, 256, 0, stream>>>(W1, W2, W1ph, W1pl, W2ph, W2pl);
    k_init<<<(NN * 32 + 255) / 256, 256, 0, stream>>>(x, W_x, bsum_x, h16);
    k_hist<<<(NE + 255) / 256, 256, 0, stream>>>(dst, counts);
    k_scan1<<<SCAN_B, 256, 0, stream>>>(counts, bsum);
    k_scan2<<<1, 256, 0, stream>>>(bsum, bpre, row_start);
    k_scan3<<<SCAN_B, 256, 0, stream>>>(counts, bpre, row_start);
    k_fill<<<(NE + 255) / 256, 256, 0, stream>>>(src, dst, edge_attr, row_start, cursor,
                                                 sorted_pk);
    k_esum<<<SCAN_B, 256, 0, stream>>>(sorted_pk, row_start, attsum, sorted_srcc);
    const int AGG_GRID = (NN * 64 + 255) / 256;
    for (int l = 0; l < NL; ++l) {
        if (l == 0) {
            k_agg<0><<<AGG_GRID, 256, 0, stream>>>(
                h16, sorted_srcc, attsum, scsh,
                W_e + (size_t)l * EF * EMB, bsum_e + l * EMB, row_start,
                agg16, stats);
        } else {
            k_agg<1><<<AGG_GRID, 256, 0, stream>>>(
                z16, sorted_srcc, attsum, scsh,
                W_e + (size_t)l * EF * EMB, bsum_e + l * EMB, row_start,
                agg16, stats);
        }
        k_mlp<<<(NN + 31) / 32, 256, 0, stream>>>(
            agg16,
            W1ph + (size_t)l * HID * EMB, W1pl + (size_t)l * HID * EMB, b1 + (size_t)l * HID,
            W2ph + (size_t)l * EMB * HID, W2pl + (size_t)l * EMB * HID, b2 + (size_t)l * EMB,
            z16, stats);
        k_bnscale<<<1, 128, 0, stream>>>(stats, gamma + l * EMB, beta + l * EMB, scsh);
    }
    k_bn<<<(NN * EMB / 4 + 255) / 256, 256, 0, stream>>>(z16, scsh, fout);
}

// Round 14
// 613.596 us; speedup vs baseline: 1.3998x; 1.0067x over previous
//
#include <hip/hip_runtime.h>
#include <math.h>

#define NN 50000
#define NE 800000
#define EMB 128
#define HID 256
#define NF 7
#define EF 5
#define NL 5
#define BN_EPS 1e-5f
#define NREP 32     // stats replicas to kill same-line atomic serialization
#define SCAN_B 196  // ceil(NN/256)

typedef _Float16 f16x8 __attribute__((ext_vector_type(8)));
typedef _Float16 f16x2 __attribute__((ext_vector_type(2)));
typedef __attribute__((ext_vector_type(4))) float f32x4;

// fp16 pack/unpack
__device__ inline unsigned pkh2(float a, float b) {
    union { unsigned v; _Float16 h[2]; } x;
    x.h[0] = (_Float16)a; x.h[1] = (_Float16)b;
    return x.v;
}
__device__ inline float2 uph2(unsigned u) {
    union { unsigned v; _Float16 h[2]; } x; x.v = u;
    return make_float2((float)x.h[0], (float)x.h[1]);
}
__device__ inline unsigned short f2h_bits(float f) {
    _Float16 h = (_Float16)f;
    return __builtin_bit_cast(unsigned short, h);
}
__device__ inline float h_bits2f(unsigned short b) {
    return (float)__builtin_bit_cast(_Float16, b);
}
__device__ inline f16x2 as_h2(unsigned u) { return __builtin_bit_cast(f16x2, u); }

// ---------------------------------------------------------------------------
// k_prep: block 0 computes bias-sum vectors; all blocks zero CSR counts/cursor
// ---------------------------------------------------------------------------
__global__ void k_prep(const float* __restrict__ b_x, const float* __restrict__ b_e,
                       float* __restrict__ bsum_x, float* __restrict__ bsum_e,
                       int* __restrict__ counts, int* __restrict__ cursor) {
    int tid = threadIdx.x;
    if (blockIdx.x == 0 && tid < EMB) {
        float s = 0.f;
        for (int f = 0; f < NF; ++f) s += b_x[f * EMB + tid];
        bsum_x[tid] = s;
        for (int l = 0; l < NL; ++l) {
            float se = 0.f;
            for (int f = 0; f < EF; ++f) se += b_e[(l * EF + f) * EMB + tid];
            bsum_e[l * EMB + tid] = se;
        }
    }
    int gid = blockIdx.x * blockDim.x + tid;
    int stride = gridDim.x * blockDim.x;
    for (int i = gid; i < NN; i += stride) { counts[i] = 0; cursor[i] = 0; }
}

// ---------------------------------------------------------------------------
// k_prepw: fragment-pack + fp16 hi/lo split of weights (combined rel ~2^-22).
// W1p layout: [L][wave(4)][h2(4)][kk(4)][lane(64)][j(8)]  (lane-contiguous 16B)
// W2p layout: [L][wave(4)][o2(2)][kk(8)][lane(64)][j(8)]
// ---------------------------------------------------------------------------
__global__ void k_prepw(const float* __restrict__ W1, const float* __restrict__ W2,
                        unsigned short* __restrict__ W1ph, unsigned short* __restrict__ W1pl,
                        unsigned short* __restrict__ W2ph, unsigned short* __restrict__ W2pl) {
    const int TOT = NL * EMB * HID;   // 163840 per matrix
    int gid = blockIdx.x * blockDim.x + threadIdx.x;
    if (gid < TOT) {
        int l = gid / (EMB * HID);
        int r = gid % (EMB * HID);             // 32768
        int w = r >> 13;                       // /8192
        int rem = r & 8191;
        int h2 = rem >> 11;                    // /2048
        int rem2 = rem & 2047;
        int kk = rem2 >> 9;                    // /512
        int rem3 = rem2 & 511;
        int lane = rem3 >> 3;
        int j = rem3 & 7;
        int hc = w * 64 + h2 * 16 + (lane & 15);
        int k = kk * 32 + (lane >> 4) * 8 + j;
        float wv = W1[((size_t)l * EMB + k) * HID + hc];
        unsigned short hi = f2h_bits(wv);
        W1ph[gid] = hi;
        W1pl[gid] = f2h_bits(wv - h_bits2f(hi));
    } else if (gid < 2 * TOT) {
        int g = gid - TOT;
        int l = g / (EMB * HID);
        int r = g % (EMB * HID);
        int w = r >> 13;
        int rem = r & 8191;
        int o2 = rem >> 12;                    // /4096
        int rem2 = rem & 4095;
        int kk = rem2 >> 9;
        int rem3 = rem2 & 511;
        int lane = rem3 >> 3;
        int j = rem3 & 7;
        int oc = w * 32 + o2 * 16 + (lane & 15);
        int k2 = kk * 32 + (lane >> 4) * 8 + j;
        float wv = W2[((size_t)l * HID + k2) * EMB + oc];
        unsigned short hi = f2h_bits(wv);
        W2ph[g] = hi;
        W2pl[g] = f2h_bits(wv - h_bits2f(hi));
    }
}

// ---------------------------------------------------------------------------
// k_init: h(fp16) = x @ W_x + bsum_x  (32 threads/node, 4 cols each)
// ---------------------------------------------------------------------------
__global__ void k_init(const float* __restrict__ x, const float* __restrict__ W_x,
                       const float* __restrict__ bsum_x, unsigned short* __restrict__ h16) {
    int gid = blockIdx.x * blockDim.x + threadIdx.x;
    int v = gid >> 5;
    if (v >= NN) return;
    int c = (gid & 31) << 2;
    float4 acc = *(const float4*)(bsum_x + c);
    #pragma unroll
    for (int f = 0; f < NF; ++f) {
        float xv = x[(size_t)v * NF + f];
        float4 w = *(const float4*)(W_x + f * EMB + c);
        acc.x += xv * w.x; acc.y += xv * w.y; acc.z += xv * w.z; acc.w += xv * w.w;
    }
    uint2 p = make_uint2(pkh2(acc.x, acc.y), pkh2(acc.z, acc.w));
    *(uint2*)(h16 + (size_t)v * EMB + c) = p;
}

// ---------------------------------------------------------------------------
// CSR build: histogram of dst, 3-phase multi-block scan, packed bucket fill
// ---------------------------------------------------------------------------
__global__ void k_hist(const int* __restrict__ dst, int* __restrict__ counts) {
    int e = blockIdx.x * blockDim.x + threadIdx.x;
    if (e < NE) atomicAdd(&counts[dst[e]], 1);
}

__global__ void k_scan1(const int* __restrict__ counts, int* __restrict__ bsum) {
    int tid = threadIdx.x;
    int i = blockIdx.x * 256 + tid;
    int v = (i < NN) ? counts[i] : 0;
    #pragma unroll
    for (int off = 1; off < 64; off <<= 1) v += __shfl_xor(v, off, 64);
    __shared__ int ws[4];
    if ((tid & 63) == 0) ws[tid >> 6] = v;
    __syncthreads();
    if (tid == 0) bsum[blockIdx.x] = ws[0] + ws[1] + ws[2] + ws[3];
}

__global__ void k_scan2(const int* __restrict__ bsum, int* __restrict__ bpre,
                        int* __restrict__ row_start) {
    int tid = threadIdx.x;  // 256 threads
    int x = (tid < SCAN_B) ? bsum[tid] : 0;
    int lane = tid & 63, wv = tid >> 6;
    int v = x;
    #pragma unroll
    for (int off = 1; off < 64; off <<= 1) {
        int t = __shfl_up(v, off, 64);
        if (lane >= off) v += t;
    }
    __shared__ int wsum[4];
    if (lane == 63) wsum[wv] = v;
    __syncthreads();
    int woff = 0;
    #pragma unroll
    for (int w = 0; w < 4; ++w) if (w < wv) woff += wsum[w];
    int incl = v + woff;
    if (tid < SCAN_B) bpre[tid] = incl - x;
    if (tid == 255) row_start[NN] = incl;
}

__global__ void k_scan3(const int* __restrict__ counts, const int* __restrict__ bpre,
                        int* __restrict__ row_start) {
    int tid = threadIdx.x;
    int i = blockIdx.x * 256 + tid;
    int x = (i < NN) ? counts[i] : 0;
    int lane = tid & 63, wv = tid >> 6;
    int v = x;
    #pragma unroll
    for (int off = 1; off < 64; off <<= 1) {
        int t = __shfl_up(v, off, 64);
        if (lane >= off) v += t;
    }
    __shared__ int wsum[4];
    if (lane == 63) wsum[wv] = v;
    __syncthreads();
    int woff = 0;
    #pragma unroll
    for (int w = 0; w < 4; ++w) if (w < wv) woff += wsum[w];
    if (i < NN) row_start[i] = bpre[blockIdx.x] + v + woff - x;
}

// k_fill: ONE 16-B scatter per edge: {src, fp16 ea0..ea4}  (known-good ~52us).
__global__ void k_fill(const int* __restrict__ src, const int* __restrict__ dst,
                       const float* __restrict__ edge_attr,
                       const int* __restrict__ row_start, int* __restrict__ cursor,
                       uint4* __restrict__ sorted_pk) {
    int e = blockIdx.x * blockDim.x + threadIdx.x;
    if (e >= NE) return;
    int d = dst[e];
    int pos = atomicAdd(&cursor[d], 1);
    int idx = row_start[d] + pos;
    const float* ea = edge_attr + (size_t)e * EF;
    float a0 = ea[0], a1 = ea[1], a2 = ea[2], a3 = ea[3], a4 = ea[4];
    uint4 pk;
    pk.x = (unsigned)src[e];
    pk.y = pkh2(a0, a1);
    pk.z = pkh2(a2, a3);
    pk.w = pkh2(a4, 0.f);
    sorted_pk[idx] = pk;
}

// ---------------------------------------------------------------------------
// k_esum (once): per node, sum incoming edge attrs -> attsum[v][8] =
// {a0..a4, deg, 0, 0}; emit compact sorted_srcc[e] (sequential write).
// ---------------------------------------------------------------------------
__global__ void k_esum(const uint4* __restrict__ sorted_pk,
                       const int* __restrict__ row_start,
                       float* __restrict__ attsum, int* __restrict__ sorted_srcc) {
    int v = blockIdx.x * blockDim.x + threadIdx.x;
    if (v >= NN) return;
    int e0 = row_start[v], e1 = row_start[v + 1];
    float s0 = 0.f, s1 = 0.f, s2 = 0.f, s3 = 0.f, s4 = 0.f;
    for (int e = e0; e < e1; ++e) {
        uint4 pk = sorted_pk[e];
        sorted_srcc[e] = (int)pk.x;
        float2 a01 = uph2(pk.y), a23 = uph2(pk.z), a4x = uph2(pk.w);
        s0 += a01.x; s1 += a01.y; s2 += a23.x; s3 += a23.y; s4 += a4x.x;
    }
    float* o = attsum + (size_t)v * 8;
    *(float4*)(o) = make_float4(s0, s1, s2, s3);
    *(float4*)(o + 4) = make_float4(s4, (float)(e1 - e0), 0.f, 0.f);
}

// ---------------------------------------------------------------------------
// k_agg: agg[v] = h[v] + (deg+1)*bs + attsum[v]@W_e + sum_e h[src]  (h always
// a materialized fp16 plane — BN+ELU un-folded back into k_bn: the folded
// transform was 16x redundant and v_exp-heavy, 52% VALUBusy).
// One wave per node, 2 cols/lane, unroll-8 readfirstlane'd SGPR-base gathers.
// Inner accumulation: packed-fp16 tree (7 v_pk_add_f16 per 8 edges) + one
// fp32 flush — ~1.5 VALU/edge vs ~8. Blocks 0..31 zero BN-stats replicas.
// ---------------------------------------------------------------------------
__global__ __launch_bounds__(256) void k_agg(
        const unsigned short* __restrict__ h16, const int* __restrict__ sorted_srcc,
        const float* __restrict__ attsum,
        const float* __restrict__ W_e_l, const float* __restrict__ bsum_e_l,
        const int* __restrict__ row_start,
        unsigned short* __restrict__ agg16, float* __restrict__ stats) {
    int tid = threadIdx.x;
    if (blockIdx.x < NREP) stats[blockIdx.x * 2 * EMB + tid] = 0.f;  // 256 == 2*EMB
    int gid = blockIdx.x * 256 + tid;
    int v = gid >> 6;
    if (v >= NN) return;
    int c = (gid & 63) << 1;
    float2 we0 = *(const float2*)(W_e_l + 0 * EMB + c);
    float2 we1 = *(const float2*)(W_e_l + 1 * EMB + c);
    float2 we2 = *(const float2*)(W_e_l + 2 * EMB + c);
    float2 we3 = *(const float2*)(W_e_l + 3 * EMB + c);
    float2 we4 = *(const float2*)(W_e_l + 4 * EMB + c);
    float2 bs = *(const float2*)(bsum_e_l + c);
    float2 hv = uph2(*(const unsigned*)(h16 + (size_t)v * EMB + c));
    const float* at = attsum + (size_t)v * 8;
    float4 a03 = *(const float4*)(at);
    float2 a45 = *(const float2*)(at + 4);   // a4, deg
    float ax = hv.x + (a45.y + 1.f) * bs.x
             + a03.x*we0.x + a03.y*we1.x + a03.z*we2.x + a03.w*we3.x + a45.x*we4.x;
    float ay = hv.y + (a45.y + 1.f) * bs.y
             + a03.x*we0.y + a03.y*we1.y + a03.z*we2.y + a03.w*we3.y + a45.x*we4.y;
    int e0 = row_start[v], e1 = row_start[v + 1];
    int e = e0;
    for (; e + 8 <= e1; e += 8) {
        int s0 = __builtin_amdgcn_readfirstlane(sorted_srcc[e + 0]);
        int s1 = __builtin_amdgcn_readfirstlane(sorted_srcc[e + 1]);
        int s2 = __builtin_amdgcn_readfirstlane(sorted_srcc[e + 2]);
        int s3 = __builtin_amdgcn_readfirstlane(sorted_srcc[e + 3]);
        int s4 = __builtin_amdgcn_readfirstlane(sorted_srcc[e + 4]);
        int s5 = __builtin_amdgcn_readfirstlane(sorted_srcc[e + 5]);
        int s6 = __builtin_amdgcn_readfirstlane(sorted_srcc[e + 6]);
        int s7 = __builtin_amdgcn_readfirstlane(sorted_srcc[e + 7]);
        unsigned u0 = *(const unsigned*)(h16 + (size_t)s0 * EMB + c);
        unsigned u1 = *(const unsigned*)(h16 + (size_t)s1 * EMB + c);
        unsigned u2 = *(const unsigned*)(h16 + (size_t)s2 * EMB + c);
        unsigned u3 = *(const unsigned*)(h16 + (size_t)s3 * EMB + c);
        unsigned u4 = *(const unsigned*)(h16 + (size_t)s4 * EMB + c);
        unsigned u5 = *(const unsigned*)(h16 + (size_t)s5 * EMB + c);
        unsigned u6 = *(const unsigned*)(h16 + (size_t)s6 * EMB + c);
        unsigned u7 = *(const unsigned*)(h16 + (size_t)s7 * EMB + c);
        // packed fp16 tree: 7 pk_adds, then one fp32 flush
        f16x2 p01 = as_h2(u0) + as_h2(u1);
        f16x2 p23 = as_h2(u2) + as_h2(u3);
        f16x2 p45 = as_h2(u4) + as_h2(u5);
        f16x2 p67 = as_h2(u6) + as_h2(u7);
        f16x2 p03 = p01 + p23;
        f16x2 p47 = p45 + p67;
        f16x2 p07 = p03 + p47;
        ax += (float)p07.x;
        ay += (float)p07.y;
    }
    for (; e < e1; ++e) {
        int s = __builtin_amdgcn_readfirstlane(sorted_srcc[e]);
        float2 hs = uph2(*(const unsigned*)(h16 + (size_t)s * EMB + c));
        ax += hs.x;
        ay += hs.y;
    }
    *(unsigned*)(agg16 + (size_t)v * EMB + c) = pkh2(ax, ay);
}

// ---------------------------------------------------------------------------
// k_mlp (f16 MFMA): activations single fp16 plane, weights fp16 hi/lo.
// 2-term MFMA both phases (128 MFMA/wave); LDS 25 KB -> ~5-6 blocks/CU.
// 32-row tile, 4 waves. D-frag: col=lane&15 (node), row=quad*4+reg.
// Writes z fp16; BN stats -> replicated buffers (blockIdx&31).
// ---------------------------------------------------------------------------
__global__ __launch_bounds__(256) void k_mlp(
        const unsigned short* __restrict__ agg16,
        const unsigned short* __restrict__ W1ph, const unsigned short* __restrict__ W1pl,
        const float* __restrict__ b1_l,
        const unsigned short* __restrict__ W2ph, const unsigned short* __restrict__ W2pl,
        const float* __restrict__ b2_l,
        unsigned short* __restrict__ z16, float* __restrict__ stats) {
    __shared__ unsigned short A16[32][136];    // 8.5 KB  (+8 pad)
    __shared__ unsigned short Hid16[32][264];  // 16.5 KB (+8 pad)
    int tid = threadIdx.x;
    int r0 = blockIdx.x * 32;
    int rep = blockIdx.x & (NREP - 1);
    // stage A tile (zero-pad rows >= NN): 512 lane-16B loads = 2 iterations
    #pragma unroll
    for (int it = 0; it < 2; ++it) {
        int idx = it * 256 + tid;       // 0..511
        int row = idx >> 4;
        int cb = (idx & 15) * 8;
        int grow = r0 + row;
        uint4 val = make_uint4(0u, 0u, 0u, 0u);
        if (grow < NN) val = *(const uint4*)(agg16 + (size_t)grow * EMB + cb);
        *(uint4*)(&A16[row][cb]) = val;
    }
    __syncthreads();
    int wave = tid >> 6, lane = tid & 63;
    int l16 = lane & 15, quad = lane >> 4;
    // ---- phase 1: wave owns hid cols [64*wave, 64*wave+64)
    {
        f16x8 af[2][4];
        #pragma unroll
        for (int nt = 0; nt < 2; ++nt)
            #pragma unroll
            for (int kk = 0; kk < 4; ++kk)
                af[nt][kk] = *(const f16x8*)(&A16[nt * 16 + l16][kk * 32 + quad * 8]);
        #pragma unroll
        for (int h2 = 0; h2 < 4; ++h2) {
            f16x8 whf[4], wlf[4];
            #pragma unroll
            for (int kk = 0; kk < 4; ++kk) {
                size_t off = ((((size_t)(wave * 4 + h2) * 4) + kk) * 64 + lane) * 8;
                whf[kk] = *(const f16x8*)(W1ph + off);
                wlf[kk] = *(const f16x8*)(W1pl + off);
            }
            float4 bv = *(const float4*)(b1_l + wave * 64 + h2 * 16 + quad * 4);
            f32x4 bias = {bv.x, bv.y, bv.z, bv.w};
            #pragma unroll
            for (int nt = 0; nt < 2; ++nt) {
                f32x4 acc = bias;
                #pragma unroll
                for (int kk = 0; kk < 4; ++kk)
                    acc = __builtin_amdgcn_mfma_f32_16x16x32_f16(whf[kk], af[nt][kk], acc, 0, 0, 0);
                #pragma unroll
                for (int kk = 0; kk < 4; ++kk)
                    acc = __builtin_amdgcn_mfma_f32_16x16x32_f16(wlf[kk], af[nt][kk], acc, 0, 0, 0);
                uint2 p;
                p.x = pkh2(fmaxf(acc[0], 0.f), fmaxf(acc[1], 0.f));
                p.y = pkh2(fmaxf(acc[2], 0.f), fmaxf(acc[3], 0.f));
                int col = wave * 64 + h2 * 16 + quad * 4;
                *(uint2*)(&Hid16[nt * 16 + l16][col]) = p;
            }
        }
    }
    __syncthreads();
    // ---- phase 2: wave owns out cols [32*wave, 32*wave+32)
    float ss[2][4] = {}, sq[2][4] = {};
    #pragma unroll
    for (int o2 = 0; o2 < 2; ++o2) {
        f16x8 w2h[8], w2l[8];
        #pragma unroll
        for (int kk = 0; kk < 8; ++kk) {
            size_t off = ((((size_t)(wave * 2 + o2) * 8) + kk) * 64 + lane) * 8;
            w2h[kk] = *(const f16x8*)(W2ph + off);
            w2l[kk] = *(const f16x8*)(W2pl + off);
        }
        float4 bv = *(const float4*)(b2_l + wave * 32 + o2 * 16 + quad * 4);
        f32x4 bias = {bv.x, bv.y, bv.z, bv.w};
        #pragma unroll
        for (int nt = 0; nt < 2; ++nt) {
            f16x8 hf[8];
            #pragma unroll
            for (int kk = 0; kk < 8; ++kk)
                hf[kk] = *(const f16x8*)(&Hid16[nt * 16 + l16][kk * 32 + quad * 8]);
            f32x4 acc = bias;
            #pragma unroll
            for (int kk = 0; kk < 8; ++kk)
                acc = __builtin_amdgcn_mfma_f32_16x16x32_f16(w2h[kk], hf[kk], acc, 0, 0, 0);
            #pragma unroll
            for (int kk = 0; kk < 8; ++kk)
                acc = __builtin_amdgcn_mfma_f32_16x16x32_f16(w2l[kk], hf[kk], acc, 0, 0, 0);
            int node = r0 + nt * 16 + l16;
            if (node < NN) {
                uint2 p = make_uint2(pkh2(acc[0], acc[1]), pkh2(acc[2], acc[3]));
                *(uint2*)(z16 + (size_t)node * EMB + wave * 32 + o2 * 16 + quad * 4) = p;
                #pragma unroll
                for (int r = 0; r < 4; ++r) {
                    ss[o2][r] += acc[r];
                    sq[o2][r] += acc[r] * acc[r];
                }
            }
        }
    }
    #pragma unroll
    for (int o2 = 0; o2 < 2; ++o2)
        #pragma unroll
        for (int r = 0; r < 4; ++r) {
            float s = ss[o2][r], q = sq[o2][r];
            #pragma unroll
            for (int m = 1; m < 16; m <<= 1) {
                s += __shfl_xor(s, m, 64);
                q += __shfl_xor(q, m, 64);
            }
            if (l16 == 0) {
                int oc = wave * 32 + o2 * 16 + quad * 4 + r;
                atomicAdd(&stats[rep * 2 * EMB + oc], s);
                atomicAdd(&stats[rep * 2 * EMB + EMB + oc], q);
            }
        }
}

// ---------------------------------------------------------------------------
// k_bnscale: ONE block reduces the NREP stats replicas -> sc/sh (1 KB).
// (Next layer's k_agg re-zeroes the replicas.)
// ---------------------------------------------------------------------------
__global__ void k_bnscale(const float* __restrict__ stats,
                          const float* __restrict__ gamma_l, const float* __restrict__ beta_l,
                          float* __restrict__ scsh) {
    int tid = threadIdx.x;  // 128 threads
    float s = 0.f, q = 0.f;
    #pragma unroll
    for (int r = 0; r < NREP; ++r) {
        s += stats[r * 2 * EMB + tid];
        q += stats[r * 2 * EMB + EMB + tid];
    }
    float mu = s * (1.f / NN);
    float var = q * (1.f / NN) - mu * mu;
    float sf = gamma_l[tid] * rsqrtf(var + BN_EPS);
    scsh[tid] = sf;
    scsh[EMB + tid] = beta_l[tid] - mu * sf;
}

// ---------------------------------------------------------------------------
// k_bn: z16 -> BN; ELU -> fp16 h (layers 0..3) or fp32 d_out (last layer).
// Materialized ONCE per layer (6.4M transforms) vs folded-in-gather (102M).
// ---------------------------------------------------------------------------
__global__ void k_bn(const unsigned short* __restrict__ z16, const float* __restrict__ scsh,
                     unsigned short* __restrict__ h16, float* __restrict__ fout, int last) {
    __shared__ float sc[EMB], sh[EMB];
    int tid = threadIdx.x;
    if (tid < EMB) {
        sc[tid] = scsh[tid];
        sh[tid] = scsh[EMB + tid];
    }
    __syncthreads();
    int gid = blockIdx.x * blockDim.x + tid;
    if (gid >= NN * EMB / 4) return;
    int c = (gid & 31) << 2;
    uint2 zp = *(const uint2*)(z16 + (size_t)gid * 4);
    float2 z01 = uph2(zp.x), z23 = uph2(zp.y);
    float o0 = z01.x * sc[c + 0] + sh[c + 0];
    float o1 = z01.y * sc[c + 1] + sh[c + 1];
    float o2 = z23.x * sc[c + 2] + sh[c + 2];
    float o3 = z23.y * sc[c + 3] + sh[c + 3];
    if (!last) {
        o0 = (o0 > 0.f) ? o0 : (__expf(o0) - 1.f);
        o1 = (o1 > 0.f) ? o1 : (__expf(o1) - 1.f);
        o2 = (o2 > 0.f) ? o2 : (__expf(o2) - 1.f);
        o3 = (o3 > 0.f) ? o3 : (__expf(o3) - 1.f);
        uint2 p = make_uint2(pkh2(o0, o1), pkh2(o2, o3));
        *(uint2*)(h16 + (size_t)gid * 4) = p;
    } else {
        *(float4*)(fout + (size_t)gid * 4) = make_float4(o0, o1, o2, o3);
    }
}

// ---------------------------------------------------------------------------
extern "C" void kernel_launch(void* const* d_in, const int* in_sizes, int n_in,
                              void* d_out, int out_size, void* d_ws, size_t ws_size,
                              hipStream_t stream) {
    const float* x         = (const float*)d_in[0];
    const float* edge_attr = (const float*)d_in[1];
    const int*   edge_idx  = (const int*)d_in[2];
    const float* W_x   = (const float*)d_in[3];
    const float* b_x   = (const float*)d_in[4];
    const float* W_e   = (const float*)d_in[5];
    const float* b_e   = (const float*)d_in[6];
    const float* W1    = (const float*)d_in[7];
    const float* b1    = (const float*)d_in[8];
    const float* W2    = (const float*)d_in[9];
    const float* b2    = (const float*)d_in[10];
    const float* gamma = (const float*)d_in[11];
    const float* beta  = (const float*)d_in[12];
    float* fout = (float*)d_out;  // final BN writes fp32 here

    const int* src = edge_idx;
    const int* dst = edge_idx + NE;

    char* p = (char*)d_ws;
    auto alloc = [&](size_t bytes) { char* q = p; p += (bytes + 255) & ~(size_t)255; return q; };
    unsigned short* h16  = (unsigned short*)alloc((size_t)NN * EMB * 2);
    unsigned short* z16  = (unsigned short*)alloc((size_t)NN * EMB * 2);
    unsigned short* agg16 = (unsigned short*)alloc((size_t)NN * EMB * 2);
    unsigned short* W1ph = (unsigned short*)alloc((size_t)NL * HID * EMB * 2);
    unsigned short* W1pl = (unsigned short*)alloc((size_t)NL * HID * EMB * 2);
    unsigned short* W2ph = (unsigned short*)alloc((size_t)NL * EMB * HID * 2);
    unsigned short* W2pl = (unsigned short*)alloc((size_t)NL * EMB * HID * 2);
    int*   row_start  = (int*)alloc((NN + 1) * sizeof(int));
    int*   counts     = (int*)alloc(NN * sizeof(int));
    int*   cursor     = (int*)alloc(NN * sizeof(int));
    uint4* sorted_pk  = (uint4*)alloc((size_t)NE * sizeof(uint4));
    int*   sorted_srcc= (int*)alloc((size_t)NE * sizeof(int));
    float* attsum     = (float*)alloc((size_t)NN * 8 * sizeof(float));
    int*   bsum       = (int*)alloc(SCAN_B * sizeof(int));
    int*   bpre       = (int*)alloc(SCAN_B * sizeof(int));
    float* stats      = (float*)alloc((size_t)NREP * 2 * EMB * sizeof(float));
    float* scsh       = (float*)alloc(2 * EMB * sizeof(float));
    float* bsum_x     = (float*)alloc(EMB * sizeof(float));
    float* bsum_e     = (float*)alloc(NL * EMB * sizeof(float));

    k_prep<<<256, 256, 0, stream>>>(b_x, b_e, bsum_x, bsum_e, counts, cursor);
    k_prepw<<<(2 * NL * EMB * HID + 255) / 256, 256, 0, stream>>>(W1, W2, W1ph, W1pl, W2ph, W2pl);
    k_init<<<(NN * 32 + 255) / 256, 256, 0, stream>>>(x, W_x, bsum_x, h16);
    k_hist<<<(NE + 255) / 256, 256, 0, stream>>>(dst, counts);
    k_scan1<<<SCAN_B, 256, 0, stream>>>(counts, bsum);
    k_scan2<<<1, 256, 0, stream>>>(bsum, bpre, row_start);
    k_scan3<<<SCAN_B, 256, 0, stream>>>(counts, bpre, row_start);
    k_fill<<<(NE + 255) / 256, 256, 0, stream>>>(src, dst, edge_attr, row_start, cursor,
                                                 sorted_pk);
    k_esum<<<SCAN_B, 256, 0, stream>>>(sorted_pk, row_start, attsum, sorted_srcc);
    const int AGG_GRID = (NN * 64 + 255) / 256;
    for (int l = 0; l < NL; ++l) {
        k_agg<<<AGG_GRID, 256, 0, stream>>>(
            h16, sorted_srcc, attsum,
            W_e + (size_t)l * EF * EMB, bsum_e + l * EMB, row_start,
            agg16, stats);
        k_mlp<<<(NN + 31) / 32, 256, 0, stream>>>(
            agg16,
            W1ph + (size_t)l * HID * EMB, W1pl + (size_t)l * HID * EMB, b1 + (size_t)l * HID,
            W2ph + (size_t)l * EMB * HID, W2pl + (size_t)l * EMB * HID, b2 + (size_t)l * EMB,
            z16, stats);
        k_bnscale<<<1, 128, 0, stream>>>(stats, gamma + l * EMB, beta + l * EMB, scsh);
        k_bn<<<(NN * EMB / 4 + 255) / 256, 256, 0, stream>>>(
            z16, scsh, h16, fout, (l == NL - 1) ? 1 : 0);
    }
}

// Round 15
// 581.116 us; speedup vs baseline: 1.4780x; 1.0559x over previous
//
#include <hip/hip_runtime.h>
#include <math.h>

#define NN 50000
#define NE 800000
#define EMB 128
#define HID 256
#define NF 7
#define EF 5
#define NL 5
#define BN_EPS 1e-5f
#define NREP 32     // stats replicas to kill same-line atomic serialization
#define SCAN_B 196  // ceil(NN/256)
#define NBUCK 49    // ceil(NN/1024) coarse dst-buckets for the 2-phase fill

typedef _Float16 f16x8 __attribute__((ext_vector_type(8)));
typedef _Float16 f16x2 __attribute__((ext_vector_type(2)));
typedef __attribute__((ext_vector_type(4))) float f32x4;

// fp16 pack/unpack
__device__ inline unsigned pkh2(float a, float b) {
    union { unsigned v; _Float16 h[2]; } x;
    x.h[0] = (_Float16)a; x.h[1] = (_Float16)b;
    return x.v;
}
__device__ inline float2 uph2(unsigned u) {
    union { unsigned v; _Float16 h[2]; } x; x.v = u;
    return make_float2((float)x.h[0], (float)x.h[1]);
}
__device__ inline unsigned short f2h_bits(float f) {
    _Float16 h = (_Float16)f;
    return __builtin_bit_cast(unsigned short, h);
}
__device__ inline float h_bits2f(unsigned short b) {
    return (float)__builtin_bit_cast(_Float16, b);
}
__device__ inline f16x2 as_h2(unsigned u) { return __builtin_bit_cast(f16x2, u); }

// ---------------------------------------------------------------------------
// k_prep: block 0 computes bias-sum vectors; all blocks zero CSR counts/cursor
// ---------------------------------------------------------------------------
__global__ void k_prep(const float* __restrict__ b_x, const float* __restrict__ b_e,
                       float* __restrict__ bsum_x, float* __restrict__ bsum_e,
                       int* __restrict__ counts, int* __restrict__ cursor) {
    int tid = threadIdx.x;
    if (blockIdx.x == 0 && tid < EMB) {
        float s = 0.f;
        for (int f = 0; f < NF; ++f) s += b_x[f * EMB + tid];
        bsum_x[tid] = s;
        for (int l = 0; l < NL; ++l) {
            float se = 0.f;
            for (int f = 0; f < EF; ++f) se += b_e[(l * EF + f) * EMB + tid];
            bsum_e[l * EMB + tid] = se;
        }
    }
    int gid = blockIdx.x * blockDim.x + tid;
    int stride = gridDim.x * blockDim.x;
    for (int i = gid; i < NN; i += stride) { counts[i] = 0; cursor[i] = 0; }
}

// ---------------------------------------------------------------------------
// k_prepw: fragment-pack + fp16 hi/lo split of weights (combined rel ~2^-22).
// W1p layout: [L][wave(4)][h2(4)][kk(4)][lane(64)][j(8)]  (lane-contiguous 16B)
// W2p layout: [L][wave(4)][o2(2)][kk(8)][lane(64)][j(8)]
// ---------------------------------------------------------------------------
__global__ void k_prepw(const float* __restrict__ W1, const float* __restrict__ W2,
                        unsigned short* __restrict__ W1ph, unsigned short* __restrict__ W1pl,
                        unsigned short* __restrict__ W2ph, unsigned short* __restrict__ W2pl) {
    const int TOT = NL * EMB * HID;   // 163840 per matrix
    int gid = blockIdx.x * blockDim.x + threadIdx.x;
    if (gid < TOT) {
        int l = gid / (EMB * HID);
        int r = gid % (EMB * HID);             // 32768
        int w = r >> 13;                       // /8192
        int rem = r & 8191;
        int h2 = rem >> 11;                    // /2048
        int rem2 = rem & 2047;
        int kk = rem2 >> 9;                    // /512
        int rem3 = rem2 & 511;
        int lane = rem3 >> 3;
        int j = rem3 & 7;
        int hc = w * 64 + h2 * 16 + (lane & 15);
        int k = kk * 32 + (lane >> 4) * 8 + j;
        float wv = W1[((size_t)l * EMB + k) * HID + hc];
        unsigned short hi = f2h_bits(wv);
        W1ph[gid] = hi;
        W1pl[gid] = f2h_bits(wv - h_bits2f(hi));
    } else if (gid < 2 * TOT) {
        int g = gid - TOT;
        int l = g / (EMB * HID);
        int r = g % (EMB * HID);
        int w = r >> 13;
        int rem = r & 8191;
        int o2 = rem >> 12;                    // /4096
        int rem2 = rem & 4095;
        int kk = rem2 >> 9;
        int rem3 = rem2 & 511;
        int lane = rem3 >> 3;
        int j = rem3 & 7;
        int oc = w * 32 + o2 * 16 + (lane & 15);
        int k2 = kk * 32 + (lane >> 4) * 8 + j;
        float wv = W2[((size_t)l * HID + k2) * EMB + oc];
        unsigned short hi = f2h_bits(wv);
        W2ph[g] = hi;
        W2pl[g] = f2h_bits(wv - h_bits2f(hi));
    }
}

// ---------------------------------------------------------------------------
// k_init: h(fp16) = x @ W_x + bsum_x  (32 threads/node, 4 cols each)
// ---------------------------------------------------------------------------
__global__ void k_init(const float* __restrict__ x, const float* __restrict__ W_x,
                       const float* __restrict__ bsum_x, unsigned short* __restrict__ h16) {
    int gid = blockIdx.x * blockDim.x + threadIdx.x;
    int v = gid >> 5;
    if (v >= NN) return;
    int c = (gid & 31) << 2;
    float4 acc = *(const float4*)(bsum_x + c);
    #pragma unroll
    for (int f = 0; f < NF; ++f) {
        float xv = x[(size_t)v * NF + f];
        float4 w = *(const float4*)(W_x + f * EMB + c);
        acc.x += xv * w.x; acc.y += xv * w.y; acc.z += xv * w.z; acc.w += xv * w.w;
    }
    uint2 p = make_uint2(pkh2(acc.x, acc.y), pkh2(acc.z, acc.w));
    *(uint2*)(h16 + (size_t)v * EMB + c) = p;
}

// ---------------------------------------------------------------------------
// CSR build: histogram of dst, 3-phase multi-block scan
// ---------------------------------------------------------------------------
__global__ void k_hist(const int* __restrict__ dst, int* __restrict__ counts) {
    int e = blockIdx.x * blockDim.x + threadIdx.x;
    if (e < NE) atomicAdd(&counts[dst[e]], 1);
}

__global__ void k_scan1(const int* __restrict__ counts, int* __restrict__ bsum) {
    int tid = threadIdx.x;
    int i = blockIdx.x * 256 + tid;
    int v = (i < NN) ? counts[i] : 0;
    #pragma unroll
    for (int off = 1; off < 64; off <<= 1) v += __shfl_xor(v, off, 64);
    __shared__ int ws[4];
    if ((tid & 63) == 0) ws[tid >> 6] = v;
    __syncthreads();
    if (tid == 0) bsum[blockIdx.x] = ws[0] + ws[1] + ws[2] + ws[3];
}

__global__ void k_scan2(const int* __restrict__ bsum, int* __restrict__ bpre,
                        int* __restrict__ row_start) {
    int tid = threadIdx.x;  // 256 threads
    int x = (tid < SCAN_B) ? bsum[tid] : 0;
    int lane = tid & 63, wv = tid >> 6;
    int v = x;
    #pragma unroll
    for (int off = 1; off < 64; off <<= 1) {
        int t = __shfl_up(v, off, 64);
        if (lane >= off) v += t;
    }
    __shared__ int wsum[4];
    if (lane == 63) wsum[wv] = v;
    __syncthreads();
    int woff = 0;
    #pragma unroll
    for (int w = 0; w < 4; ++w) if (w < wv) woff += wsum[w];
    int incl = v + woff;
    if (tid < SCAN_B) bpre[tid] = incl - x;
    if (tid == 255) row_start[NN] = incl;
}

// scan3 also seeds the coarse-bucket cursors: bcur[b] = row_start[b*1024]
__global__ void k_scan3(const int* __restrict__ counts, const int* __restrict__ bpre,
                        int* __restrict__ row_start, int* __restrict__ bcur) {
    int tid = threadIdx.x;
    int i = blockIdx.x * 256 + tid;
    int x = (i < NN) ? counts[i] : 0;
    int lane = tid & 63, wv = tid >> 6;
    int v = x;
    #pragma unroll
    for (int off = 1; off < 64; off <<= 1) {
        int t = __shfl_up(v, off, 64);
        if (lane >= off) v += t;
    }
    __shared__ int wsum[4];
    if (lane == 63) wsum[wv] = v;
    __syncthreads();
    int woff = 0;
    #pragma unroll
    for (int w = 0; w < 4; ++w) if (w < wv) woff += wsum[w];
    if (i < NN) {
        int rs = bpre[blockIdx.x] + v + woff - x;
        row_start[i] = rs;
        if ((i & 1023) == 0) bcur[i >> 10] = rs;
    }
}

// ---------------------------------------------------------------------------
// 2-phase fill (replaces the single random 16-B scatter whose 64-B-sector
// amplification cost 51 MB WRITE / ~50us):
// k_bucket: LDS-histogram radix partition into NBUCK coarse dst-buckets.
// Appends per (block,bucket) are contiguous -> no write amplification.
// Record: {src, h(a0,a1), h(a2,a3), h(a4) | dst<<16}  (dst < 2^16).
// ---------------------------------------------------------------------------
#define BPB 2048   // edges per block
__global__ __launch_bounds__(256) void k_bucket(
        const int* __restrict__ src, const int* __restrict__ dst,
        const float* __restrict__ edge_attr,
        int* __restrict__ bcur, uint4* __restrict__ grouped) {
    __shared__ int lcnt[NBUCK];
    __shared__ int lbase[NBUCK];
    int tid = threadIdx.x;
    if (tid < NBUCK) lcnt[tid] = 0;
    __syncthreads();
    int base = blockIdx.x * BPB;
    int b_[8];
    int d_[8];
    #pragma unroll
    for (int k = 0; k < 8; ++k) {
        int e = base + k * 256 + tid;
        if (e < NE) {
            int d = dst[e];
            d_[k] = d;
            b_[k] = d >> 10;
            atomicAdd(&lcnt[b_[k]], 1);
        } else b_[k] = -1;
    }
    __syncthreads();
    if (tid < NBUCK) {
        lbase[tid] = (lcnt[tid] > 0) ? atomicAdd(&bcur[tid], lcnt[tid]) : 0;
        lcnt[tid] = 0;
    }
    __syncthreads();
    #pragma unroll
    for (int k = 0; k < 8; ++k) {
        int e = base + k * 256 + tid;
        if (e < NE) {
            int b = b_[k];
            int off = lbase[b] + atomicAdd(&lcnt[b], 1);
            const float* ea = edge_attr + (size_t)e * EF;
            uint4 pk;
            pk.x = (unsigned)src[e];
            pk.y = pkh2(ea[0], ea[1]);
            pk.z = pkh2(ea[2], ea[3]);
            pk.w = (unsigned)f2h_bits(ea[4]) | ((unsigned)d_[k] << 16);
            grouped[off] = pk;
        }
    }
}

// k_place: scatter within a ~200KB L2-resident bucket range -> sectors fill
// before writeback (predict WRITE ~16 MB vs 51).
__global__ void k_place(const uint4* __restrict__ grouped,
                        const int* __restrict__ row_start, int* __restrict__ cursor,
                        uint4* __restrict__ sorted_pk) {
    int e = blockIdx.x * blockDim.x + threadIdx.x;
    if (e >= NE) return;
    uint4 pk = grouped[e];
    int d = (int)(pk.w >> 16);
    int pos = atomicAdd(&cursor[d], 1);
    sorted_pk[row_start[d] + pos] = pk;
}

// ---------------------------------------------------------------------------
// k_esum (once): per node, sum incoming edge attrs -> attsum[v][8] =
// {a0..a4, deg, 0, 0}; emit compact sorted_srcc[e] (sequential write).
// (a4 = low half of pk.w; high half holds dst, unused here.)
// ---------------------------------------------------------------------------
__global__ void k_esum(const uint4* __restrict__ sorted_pk,
                       const int* __restrict__ row_start,
                       float* __restrict__ attsum, int* __restrict__ sorted_srcc) {
    int v = blockIdx.x * blockDim.x + threadIdx.x;
    if (v >= NN) return;
    int e0 = row_start[v], e1 = row_start[v + 1];
    float s0 = 0.f, s1 = 0.f, s2 = 0.f, s3 = 0.f, s4 = 0.f;
    for (int e = e0; e < e1; ++e) {
        uint4 pk = sorted_pk[e];
        sorted_srcc[e] = (int)pk.x;
        float2 a01 = uph2(pk.y), a23 = uph2(pk.z);
        s0 += a01.x; s1 += a01.y; s2 += a23.x; s3 += a23.y;
        s4 += h_bits2f((unsigned short)(pk.w & 0xffffu));
    }
    float* o = attsum + (size_t)v * 8;
    *(float4*)(o) = make_float4(s0, s1, s2, s3);
    *(float4*)(o + 4) = make_float4(s4, (float)(e1 - e0), 0.f, 0.f);
}

// ---------------------------------------------------------------------------
// k_agg: agg[v] = h[v] + (deg+1)*bs + attsum[v]@W_e + sum_e h[src].
// One wave per node, 2 cols/lane, unroll-8 readfirstlane'd SGPR-base gathers;
// packed-fp16 tree accumulation (7 pk_adds / 8 edges + one fp32 flush).
// Blocks 0..31 zero the BN-stats replicas for this layer.
// ---------------------------------------------------------------------------
__global__ __launch_bounds__(256) void k_agg(
        const unsigned short* __restrict__ h16, const int* __restrict__ sorted_srcc,
        const float* __restrict__ attsum,
        const float* __restrict__ W_e_l, const float* __restrict__ bsum_e_l,
        const int* __restrict__ row_start,
        unsigned short* __restrict__ agg16, float* __restrict__ stats) {
    int tid = threadIdx.x;
    if (blockIdx.x < NREP) stats[blockIdx.x * 2 * EMB + tid] = 0.f;  // 256 == 2*EMB
    int gid = blockIdx.x * 256 + tid;
    int v = gid >> 6;
    if (v >= NN) return;
    int c = (gid & 63) << 1;
    float2 we0 = *(const float2*)(W_e_l + 0 * EMB + c);
    float2 we1 = *(const float2*)(W_e_l + 1 * EMB + c);
    float2 we2 = *(const float2*)(W_e_l + 2 * EMB + c);
    float2 we3 = *(const float2*)(W_e_l + 3 * EMB + c);
    float2 we4 = *(const float2*)(W_e_l + 4 * EMB + c);
    float2 bs = *(const float2*)(bsum_e_l + c);
    float2 hv = uph2(*(const unsigned*)(h16 + (size_t)v * EMB + c));
    const float* at = attsum + (size_t)v * 8;
    float4 a03 = *(const float4*)(at);
    float2 a45 = *(const float2*)(at + 4);   // a4, deg
    float ax = hv.x + (a45.y + 1.f) * bs.x
             + a03.x*we0.x + a03.y*we1.x + a03.z*we2.x + a03.w*we3.x + a45.x*we4.x;
    float ay = hv.y + (a45.y + 1.f) * bs.y
             + a03.x*we0.y + a03.y*we1.y + a03.z*we2.y + a03.w*we3.y + a45.x*we4.y;
    int e0 = row_start[v], e1 = row_start[v + 1];
    int e = e0;
    for (; e + 8 <= e1; e += 8) {
        int s0 = __builtin_amdgcn_readfirstlane(sorted_srcc[e + 0]);
        int s1 = __builtin_amdgcn_readfirstlane(sorted_srcc[e + 1]);
        int s2 = __builtin_amdgcn_readfirstlane(sorted_srcc[e + 2]);
        int s3 = __builtin_amdgcn_readfirstlane(sorted_srcc[e + 3]);
        int s4 = __builtin_amdgcn_readfirstlane(sorted_srcc[e + 4]);
        int s5 = __builtin_amdgcn_readfirstlane(sorted_srcc[e + 5]);
        int s6 = __builtin_amdgcn_readfirstlane(sorted_srcc[e + 6]);
        int s7 = __builtin_amdgcn_readfirstlane(sorted_srcc[e + 7]);
        unsigned u0 = *(const unsigned*)(h16 + (size_t)s0 * EMB + c);
        unsigned u1 = *(const unsigned*)(h16 + (size_t)s1 * EMB + c);
        unsigned u2 = *(const unsigned*)(h16 + (size_t)s2 * EMB + c);
        unsigned u3 = *(const unsigned*)(h16 + (size_t)s3 * EMB + c);
        unsigned u4 = *(const unsigned*)(h16 + (size_t)s4 * EMB + c);
        unsigned u5 = *(const unsigned*)(h16 + (size_t)s5 * EMB + c);
        unsigned u6 = *(const unsigned*)(h16 + (size_t)s6 * EMB + c);
        unsigned u7 = *(const unsigned*)(h16 + (size_t)s7 * EMB + c);
        f16x2 p01 = as_h2(u0) + as_h2(u1);
        f16x2 p23 = as_h2(u2) + as_h2(u3);
        f16x2 p45 = as_h2(u4) + as_h2(u5);
        f16x2 p67 = as_h2(u6) + as_h2(u7);
        f16x2 p03 = p01 + p23;
        f16x2 p47 = p45 + p67;
        f16x2 p07 = p03 + p47;
        ax += (float)p07.x;
        ay += (float)p07.y;
    }
    for (; e < e1; ++e) {
        int s = __builtin_amdgcn_readfirstlane(sorted_srcc[e]);
        float2 hs = uph2(*(const unsigned*)(h16 + (size_t)s * EMB + c));
        ax += hs.x;
        ay += hs.y;
    }
    *(unsigned*)(agg16 + (size_t)v * EMB + c) = pkh2(ax, ay);
}

// ---------------------------------------------------------------------------
// k_mlp (f16 MFMA), 64-ROW TILE: halves per-node weight L2 streaming
// (782 blocks x 256 KB = 200 MB/layer vs 400). LDS 51 KB -> 3 blocks/CU.
// Activations single fp16 plane; weights fp16 hi/lo (2-term MFMA).
// D-frag: col=lane&15 (node), row=quad*4+reg. Writes z fp16; BN stats ->
// replicated buffers (blockIdx&31).
// ---------------------------------------------------------------------------
__global__ __launch_bounds__(256) void k_mlp(
        const unsigned short* __restrict__ agg16,
        const unsigned short* __restrict__ W1ph, const unsigned short* __restrict__ W1pl,
        const float* __restrict__ b1_l,
        const unsigned short* __restrict__ W2ph, const unsigned short* __restrict__ W2pl,
        const float* __restrict__ b2_l,
        unsigned short* __restrict__ z16, float* __restrict__ stats) {
    __shared__ unsigned short A16[64][136];    // 17 KB  (+8 pad)
    __shared__ unsigned short Hid16[64][264];  // 33.8 KB (+8 pad)
    int tid = threadIdx.x;
    int r0 = blockIdx.x * 64;
    int rep = blockIdx.x & (NREP - 1);
    // stage A tile (zero-pad rows >= NN): 1024 lane-16B loads = 4 iterations
    #pragma unroll
    for (int it = 0; it < 4; ++it) {
        int idx = it * 256 + tid;       // 0..1023
        int row = idx >> 4;
        int cb = (idx & 15) * 8;
        int grow = r0 + row;
        uint4 val = make_uint4(0u, 0u, 0u, 0u);
        if (grow < NN) val = *(const uint4*)(agg16 + (size_t)grow * EMB + cb);
        *(uint4*)(&A16[row][cb]) = val;
    }
    __syncthreads();
    int wave = tid >> 6, lane = tid & 63;
    int l16 = lane & 15, quad = lane >> 4;
    // ---- phase 1: wave owns hid cols [64*wave, 64*wave+64), all 64 rows
    {
        f16x8 af[4][4];
        #pragma unroll
        for (int nt = 0; nt < 4; ++nt)
            #pragma unroll
            for (int kk = 0; kk < 4; ++kk)
                af[nt][kk] = *(const f16x8*)(&A16[nt * 16 + l16][kk * 32 + quad * 8]);
        #pragma unroll
        for (int h2 = 0; h2 < 4; ++h2) {
            f16x8 whf[4], wlf[4];
            #pragma unroll
            for (int kk = 0; kk < 4; ++kk) {
                size_t off = ((((size_t)(wave * 4 + h2) * 4) + kk) * 64 + lane) * 8;
                whf[kk] = *(const f16x8*)(W1ph + off);
                wlf[kk] = *(const f16x8*)(W1pl + off);
            }
            float4 bv = *(const float4*)(b1_l + wave * 64 + h2 * 16 + quad * 4);
            f32x4 bias = {bv.x, bv.y, bv.z, bv.w};
            #pragma unroll
            for (int nt = 0; nt < 4; ++nt) {
                f32x4 acc = bias;
                #pragma unroll
                for (int kk = 0; kk < 4; ++kk)
                    acc = __builtin_amdgcn_mfma_f32_16x16x32_f16(whf[kk], af[nt][kk], acc, 0, 0, 0);
                #pragma unroll
                for (int kk = 0; kk < 4; ++kk)
                    acc = __builtin_amdgcn_mfma_f32_16x16x32_f16(wlf[kk], af[nt][kk], acc, 0, 0, 0);
                uint2 p;
                p.x = pkh2(fmaxf(acc[0], 0.f), fmaxf(acc[1], 0.f));
                p.y = pkh2(fmaxf(acc[2], 0.f), fmaxf(acc[3], 0.f));
                int col = wave * 64 + h2 * 16 + quad * 4;
                *(uint2*)(&Hid16[nt * 16 + l16][col]) = p;
            }
        }
    }
    __syncthreads();
    // ---- phase 2: wave owns out cols [32*wave, 32*wave+32), all 64 rows
    float ss[2][4] = {}, sq[2][4] = {};
    #pragma unroll
    for (int o2 = 0; o2 < 2; ++o2) {
        f16x8 w2h[8], w2l[8];
        #pragma unroll
        for (int kk = 0; kk < 8; ++kk) {
            size_t off = ((((size_t)(wave * 2 + o2) * 8) + kk) * 64 + lane) * 8;
            w2h[kk] = *(const f16x8*)(W2ph + off);
            w2l[kk] = *(const f16x8*)(W2pl + off);
        }
        float4 bv = *(const float4*)(b2_l + wave * 32 + o2 * 16 + quad * 4);
        f32x4 bias = {bv.x, bv.y, bv.z, bv.w};
        #pragma unroll
        for (int nt = 0; nt < 4; ++nt) {
            f16x8 hf[8];
            #pragma unroll
            for (int kk = 0; kk < 8; ++kk)
                hf[kk] = *(const f16x8*)(&Hid16[nt * 16 + l16][kk * 32 + quad * 8]);
            f32x4 acc = bias;
            #pragma unroll
            for (int kk = 0; kk < 8; ++kk)
                acc = __builtin_amdgcn_mfma_f32_16x16x32_f16(w2h[kk], hf[kk], acc, 0, 0, 0);
            #pragma unroll
            for (int kk = 0; kk < 8; ++kk)
                acc = __builtin_amdgcn_mfma_f32_16x16x32_f16(w2l[kk], hf[kk], acc, 0, 0, 0);
            int node = r0 + nt * 16 + l16;
            if (node < NN) {
                uint2 p = make_uint2(pkh2(acc[0], acc[1]), pkh2(acc[2], acc[3]));
                *(uint2*)(z16 + (size_t)node * EMB + wave * 32 + o2 * 16 + quad * 4) = p;
                #pragma unroll
                for (int r = 0; r < 4; ++r) {
                    ss[o2][r] += acc[r];
                    sq[o2][r] += acc[r] * acc[r];
                }
            }
        }
    }
    #pragma unroll
    for (int o2 = 0; o2 < 2; ++o2)
        #pragma unroll
        for (int r = 0; r < 4; ++r) {
            float s = ss[o2][r], q = sq[o2][r];
            #pragma unroll
            for (int m = 1; m < 16; m <<= 1) {
                s += __shfl_xor(s, m, 64);
                q += __shfl_xor(q, m, 64);
            }
            if (l16 == 0) {
                int oc = wave * 32 + o2 * 16 + quad * 4 + r;
                atomicAdd(&stats[rep * 2 * EMB + oc], s);
                atomicAdd(&stats[rep * 2 * EMB + EMB + oc], q);
            }
        }
}

// ---------------------------------------------------------------------------
// k_bnscale: ONE block reduces the NREP stats replicas -> sc/sh (1 KB).
// (Next layer's k_agg re-zeroes the replicas.)
// ---------------------------------------------------------------------------
__global__ void k_bnscale(const float* __restrict__ stats,
                          const float* __restrict__ gamma_l, const float* __restrict__ beta_l,
                          float* __restrict__ scsh) {
    int tid = threadIdx.x;  // 128 threads
    float s = 0.f, q = 0.f;
    #pragma unroll
    for (int r = 0; r < NREP; ++r) {
        s += stats[r * 2 * EMB + tid];
        q += stats[r * 2 * EMB + EMB + tid];
    }
    float mu = s * (1.f / NN);
    float var = q * (1.f / NN) - mu * mu;
    float sf = gamma_l[tid] * rsqrtf(var + BN_EPS);
    scsh[tid] = sf;
    scsh[EMB + tid] = beta_l[tid] - mu * sf;
}

// ---------------------------------------------------------------------------
// k_bn: z16 -> BN; ELU -> fp16 h (layers 0..3) or fp32 d_out (last layer).
// ---------------------------------------------------------------------------
__global__ void k_bn(const unsigned short* __restrict__ z16, const float* __restrict__ scsh,
                     unsigned short* __restrict__ h16, float* __restrict__ fout, int last) {
    __shared__ float sc[EMB], sh[EMB];
    int tid = threadIdx.x;
    if (tid < EMB) {
        sc[tid] = scsh[tid];
        sh[tid] = scsh[EMB + tid];
    }
    __syncthreads();
    int gid = blockIdx.x * blockDim.x + tid;
    if (gid >= NN * EMB / 4) return;
    int c = (gid & 31) << 2;
    uint2 zp = *(const uint2*)(z16 + (size_t)gid * 4);
    float2 z01 = uph2(zp.x), z23 = uph2(zp.y);
    float o0 = z01.x * sc[c + 0] + sh[c + 0];
    float o1 = z01.y * sc[c + 1] + sh[c + 1];
    float o2 = z23.x * sc[c + 2] + sh[c + 2];
    float o3 = z23.y * sc[c + 3] + sh[c + 3];
    if (!last) {
        o0 = (o0 > 0.f) ? o0 : (__expf(o0) - 1.f);
        o1 = (o1 > 0.f) ? o1 : (__expf(o1) - 1.f);
        o2 = (o2 > 0.f) ? o2 : (__expf(o2) - 1.f);
        o3 = (o3 > 0.f) ? o3 : (__expf(o3) - 1.f);
        uint2 p = make_uint2(pkh2(o0, o1), pkh2(o2, o3));
        *(uint2*)(h16 + (size_t)gid * 4) = p;
    } else {
        *(float4*)(fout + (size_t)gid * 4) = make_float4(o0, o1, o2, o3);
    }
}

// ---------------------------------------------------------------------------
extern "C" void kernel_launch(void* const* d_in, const int* in_sizes, int n_in,
                              void* d_out, int out_size, void* d_ws, size_t ws_size,
                              hipStream_t stream) {
    const float* x         = (const float*)d_in[0];
    const float* edge_attr = (const float*)d_in[1];
    const int*   edge_idx  = (const int*)d_in[2];
    const float* W_x   = (const float*)d_in[3];
    const float* b_x   = (const float*)d_in[4];
    const float* W_e   = (const float*)d_in[5];
    const float* b_e   = (const float*)d_in[6];
    const float* W1    = (const float*)d_in[7];
    const float* b1    = (const float*)d_in[8];
    const float* W2    = (const float*)d_in[9];
    const float* b2    = (const float*)d_in[10];
    const float* gamma = (const float*)d_in[11];
    const float* beta  = (const float*)d_in[12];
    float* fout = (float*)d_out;  // final BN writes fp32 here

    const int* src = edge_idx;
    const int* dst = edge_idx + NE;

    char* p = (char*)d_ws;
    auto alloc = [&](size_t bytes) { char* q = p; p += (bytes + 255) & ~(size_t)255; return q; };
    unsigned short* h16  = (unsigned short*)alloc((size_t)NN * EMB * 2);
    unsigned short* z16  = (unsigned short*)alloc((size_t)NN * EMB * 2);
    unsigned short* agg16 = (unsigned short*)alloc((size_t)NN * EMB * 2);
    unsigned short* W1ph = (unsigned short*)alloc((size_t)NL * HID * EMB * 2);
    unsigned short* W1pl = (unsigned short*)alloc((size_t)NL * HID * EMB * 2);
    unsigned short* W2ph = (unsigned short*)alloc((size_t)NL * EMB * HID * 2);
    unsigned short* W2pl = (unsigned short*)alloc((size_t)NL * EMB * HID * 2);
    int*   row_start  = (int*)alloc((NN + 1) * sizeof(int));
    int*   counts     = (int*)alloc(NN * sizeof(int));
    int*   cursor     = (int*)alloc(NN * sizeof(int));
    uint4* grouped    = (uint4*)alloc((size_t)NE * sizeof(uint4));
    uint4* sorted_pk  = (uint4*)alloc((size_t)NE * sizeof(uint4));
    int*   sorted_srcc= (int*)alloc((size_t)NE * sizeof(int));
    float* attsum     = (float*)alloc((size_t)NN * 8 * sizeof(float));
    int*   bsum       = (int*)alloc(SCAN_B * sizeof(int));
    int*   bpre       = (int*)alloc(SCAN_B * sizeof(int));
    int*   bcur       = (int*)alloc(NBUCK * sizeof(int));
    float* stats      = (float*)alloc((size_t)NREP * 2 * EMB * sizeof(float));
    float* scsh       = (float*)alloc(2 * EMB * sizeof(float));
    float* bsum_x     = (float*)alloc(EMB * sizeof(float));
    float* bsum_e     = (float*)alloc(NL * EMB * sizeof(float));

    k_prep<<<256, 256, 0, stream>>>(b_x, b_e, bsum_x, bsum_e, counts, cursor);
    k_prepw<<<(2 * NL * EMB * HID + 255) / 256, 256, 0, stream>>>(W1, W2, W1ph, W1pl, W2ph, W2pl);
    k_init<<<(NN * 32 + 255) / 256, 256, 0, stream>>>(x, W_x, bsum_x, h16);
    k_hist<<<(NE + 255) / 256, 256, 0, stream>>>(dst, counts);
    k_scan1<<<SCAN_B, 256, 0, stream>>>(counts, bsum);
    k_scan2<<<1, 256, 0, stream>>>(bsum, bpre, row_start);
    k_scan3<<<SCAN_B, 256, 0, stream>>>(counts, bpre, row_start, bcur);
    k_bucket<<<(NE + BPB - 1) / BPB, 256, 0, stream>>>(src, dst, edge_attr, bcur, grouped);
    k_place<<<(NE + 255) / 256, 256, 0, stream>>>(grouped, row_start, cursor, sorted_pk);
    k_esum<<<SCAN_B, 256, 0, stream>>>(sorted_pk, row_start, attsum, sorted_srcc);
    const int AGG_GRID = (NN * 64 + 255) / 256;
    for (int l = 0; l < NL; ++l) {
        k_agg<<<AGG_GRID, 256, 0, stream>>>(
            h16, sorted_srcc, attsum,
            W_e + (size_t)l * EF * EMB, bsum_e + l * EMB, row_start,
            agg16, stats);
        k_mlp<<<(NN + 63) / 64, 256, 0, stream>>>(
            agg16,
            W1ph + (size_t)l * HID * EMB, W1pl + (size_t)l * HID * EMB, b1 + (size_t)l * HID,
            W2ph + (size_t)l * EMB * HID, W2pl + (size_t)l * EMB * HID, b2 + (size_t)l * EMB,
            z16, stats);
        k_bnscale<<<1, 128, 0, stream>>>(stats, gamma + l * EMB, beta + l * EMB, scsh);
        k_bn<<<(NN * EMB / 4 + 255) / 256, 256, 0, stream>>>(
            z16, scsh, h16, fout, (l == NL - 1) ? 1 : 0);
    }
}

// Round 16
// 577.067 us; speedup vs baseline: 1.4884x; 1.0070x over previous
//
#include <hip/hip_runtime.h>
#include <math.h>

#define NN 50000
#define NE 800000
#define EMB 128
#define HID 256
#define NF 7
#define EF 5
#define NL 5
#define BN_EPS 1e-5f
#define NREP 32     // stats replicas to kill same-line atomic serialization
#define SCAN_B 196  // ceil(NN/256)
#define NBUCK 49    // ceil(NN/1024) coarse dst-buckets for the 2-phase fill

typedef _Float16 f16x8 __attribute__((ext_vector_type(8)));
typedef _Float16 f16x2 __attribute__((ext_vector_type(2)));
typedef __attribute__((ext_vector_type(4))) float f32x4;

// fp16 pack/unpack
__device__ inline unsigned pkh2(float a, float b) {
    union { unsigned v; _Float16 h[2]; } x;
    x.h[0] = (_Float16)a; x.h[1] = (_Float16)b;
    return x.v;
}
__device__ inline float2 uph2(unsigned u) {
    union { unsigned v; _Float16 h[2]; } x; x.v = u;
    return make_float2((float)x.h[0], (float)x.h[1]);
}
__device__ inline unsigned short f2h_bits(float f) {
    _Float16 h = (_Float16)f;
    return __builtin_bit_cast(unsigned short, h);
}
__device__ inline float h_bits2f(unsigned short b) {
    return (float)__builtin_bit_cast(_Float16, b);
}
__device__ inline f16x2 as_h2(unsigned u) { return __builtin_bit_cast(f16x2, u); }

// ---------------------------------------------------------------------------
// k_prep: block 0 computes bias-sum vectors; all blocks zero CSR counts/cursor
// ---------------------------------------------------------------------------
__global__ void k_prep(const float* __restrict__ b_x, const float* __restrict__ b_e,
                       float* __restrict__ bsum_x, float* __restrict__ bsum_e,
                       int* __restrict__ counts, int* __restrict__ cursor) {
    int tid = threadIdx.x;
    if (blockIdx.x == 0 && tid < EMB) {
        float s = 0.f;
        for (int f = 0; f < NF; ++f) s += b_x[f * EMB + tid];
        bsum_x[tid] = s;
        for (int l = 0; l < NL; ++l) {
            float se = 0.f;
            for (int f = 0; f < EF; ++f) se += b_e[(l * EF + f) * EMB + tid];
            bsum_e[l * EMB + tid] = se;
        }
    }
    int gid = blockIdx.x * blockDim.x + tid;
    int stride = gridDim.x * blockDim.x;
    for (int i = gid; i < NN; i += stride) { counts[i] = 0; cursor[i] = 0; }
}

// ---------------------------------------------------------------------------
// k_prepw: fragment-pack + fp16 hi/lo split of weights (combined rel ~2^-22).
// W1p layout: [L][wave(4)][h2(4)][kk(4)][lane(64)][j(8)]  (lane-contiguous 16B)
// W2p layout: [L][wave(4)][o2(2)][kk(8)][lane(64)][j(8)]
// ---------------------------------------------------------------------------
__global__ void k_prepw(const float* __restrict__ W1, const float* __restrict__ W2,
                        unsigned short* __restrict__ W1ph, unsigned short* __restrict__ W1pl,
                        unsigned short* __restrict__ W2ph, unsigned short* __restrict__ W2pl) {
    const int TOT = NL * EMB * HID;   // 163840 per matrix
    int gid = blockIdx.x * blockDim.x + threadIdx.x;
    if (gid < TOT) {
        int l = gid / (EMB * HID);
        int r = gid % (EMB * HID);             // 32768
        int w = r >> 13;                       // /8192
        int rem = r & 8191;
        int h2 = rem >> 11;                    // /2048
        int rem2 = rem & 2047;
        int kk = rem2 >> 9;                    // /512
        int rem3 = rem2 & 511;
        int lane = rem3 >> 3;
        int j = rem3 & 7;
        int hc = w * 64 + h2 * 16 + (lane & 15);
        int k = kk * 32 + (lane >> 4) * 8 + j;
        float wv = W1[((size_t)l * EMB + k) * HID + hc];
        unsigned short hi = f2h_bits(wv);
        W1ph[gid] = hi;
        W1pl[gid] = f2h_bits(wv - h_bits2f(hi));
    } else if (gid < 2 * TOT) {
        int g = gid - TOT;
        int l = g / (EMB * HID);
        int r = g % (EMB * HID);
        int w = r >> 13;
        int rem = r & 8191;
        int o2 = rem >> 12;                    // /4096
        int rem2 = rem & 4095;
        int kk = rem2 >> 9;
        int rem3 = rem2 & 511;
        int lane = rem3 >> 3;
        int j = rem3 & 7;
        int oc = w * 32 + o2 * 16 + (lane & 15);
        int k2 = kk * 32 + (lane >> 4) * 8 + j;
        float wv = W2[((size_t)l * HID + k2) * EMB + oc];
        unsigned short hi = f2h_bits(wv);
        W2ph[g] = hi;
        W2pl[g] = f2h_bits(wv - h_bits2f(hi));
    }
}

// ---------------------------------------------------------------------------
// k_init: h(fp16) = x @ W_x + bsum_x  (32 threads/node, 4 cols each)
// ---------------------------------------------------------------------------
__global__ void k_init(const float* __restrict__ x, const float* __restrict__ W_x,
                       const float* __restrict__ bsum_x, unsigned short* __restrict__ h16) {
    int gid = blockIdx.x * blockDim.x + threadIdx.x;
    int v = gid >> 5;
    if (v >= NN) return;
    int c = (gid & 31) << 2;
    float4 acc = *(const float4*)(bsum_x + c);
    #pragma unroll
    for (int f = 0; f < NF; ++f) {
        float xv = x[(size_t)v * NF + f];
        float4 w = *(const float4*)(W_x + f * EMB + c);
        acc.x += xv * w.x; acc.y += xv * w.y; acc.z += xv * w.z; acc.w += xv * w.w;
    }
    uint2 p = make_uint2(pkh2(acc.x, acc.y), pkh2(acc.z, acc.w));
    *(uint2*)(h16 + (size_t)v * EMB + c) = p;
}

// ---------------------------------------------------------------------------
// CSR build: histogram of dst, 3-phase multi-block scan
// ---------------------------------------------------------------------------
__global__ void k_hist(const int* __restrict__ dst, int* __restrict__ counts) {
    int e = blockIdx.x * blockDim.x + threadIdx.x;
    if (e < NE) atomicAdd(&counts[dst[e]], 1);
}

__global__ void k_scan1(const int* __restrict__ counts, int* __restrict__ bsum) {
    int tid = threadIdx.x;
    int i = blockIdx.x * 256 + tid;
    int v = (i < NN) ? counts[i] : 0;
    #pragma unroll
    for (int off = 1; off < 64; off <<= 1) v += __shfl_xor(v, off, 64);
    __shared__ int ws[4];
    if ((tid & 63) == 0) ws[tid >> 6] = v;
    __syncthreads();
    if (tid == 0) bsum[blockIdx.x] = ws[0] + ws[1] + ws[2] + ws[3];
}

__global__ void k_scan2(const int* __restrict__ bsum, int* __restrict__ bpre,
                        int* __restrict__ row_start) {
    int tid = threadIdx.x;  // 256 threads
    int x = (tid < SCAN_B) ? bsum[tid] : 0;
    int lane = tid & 63, wv = tid >> 6;
    int v = x;
    #pragma unroll
    for (int off = 1; off < 64; off <<= 1) {
        int t = __shfl_up(v, off, 64);
        if (lane >= off) v += t;
    }
    __shared__ int wsum[4];
    if (lane == 63) wsum[wv] = v;
    __syncthreads();
    int woff = 0;
    #pragma unroll
    for (int w = 0; w < 4; ++w) if (w < wv) woff += wsum[w];
    int incl = v + woff;
    if (tid < SCAN_B) bpre[tid] = incl - x;
    if (tid == 255) row_start[NN] = incl;
}

// scan3 also seeds the coarse-bucket cursors: bcur[b] = row_start[b*1024]
__global__ void k_scan3(const int* __restrict__ counts, const int* __restrict__ bpre,
                        int* __restrict__ row_start, int* __restrict__ bcur) {
    int tid = threadIdx.x;
    int i = blockIdx.x * 256 + tid;
    int x = (i < NN) ? counts[i] : 0;
    int lane = tid & 63, wv = tid >> 6;
    int v = x;
    #pragma unroll
    for (int off = 1; off < 64; off <<= 1) {
        int t = __shfl_up(v, off, 64);
        if (lane >= off) v += t;
    }
    __shared__ int wsum[4];
    if (lane == 63) wsum[wv] = v;
    __syncthreads();
    int woff = 0;
    #pragma unroll
    for (int w = 0; w < 4; ++w) if (w < wv) woff += wsum[w];
    if (i < NN) {
        int rs = bpre[blockIdx.x] + v + woff - x;
        row_start[i] = rs;
        if ((i & 1023) == 0) bcur[i >> 10] = rs;
    }
}

// ---------------------------------------------------------------------------
// 2-phase fill: k_bucket = LDS-histogram radix partition into NBUCK coarse
// dst-buckets (contiguous appends, no sector amplification);
// k_place = scatter within an L2-resident ~200KB bucket range.
// Record: {src, h(a0,a1), h(a2,a3), h(a4) | dst<<16}  (dst < 2^16).
// ---------------------------------------------------------------------------
#define BPB 2048   // edges per block
__global__ __launch_bounds__(256) void k_bucket(
        const int* __restrict__ src, const int* __restrict__ dst,
        const float* __restrict__ edge_attr,
        int* __restrict__ bcur, uint4* __restrict__ grouped) {
    __shared__ int lcnt[NBUCK];
    __shared__ int lbase[NBUCK];
    int tid = threadIdx.x;
    if (tid < NBUCK) lcnt[tid] = 0;
    __syncthreads();
    int base = blockIdx.x * BPB;
    int b_[8];
    int d_[8];
    #pragma unroll
    for (int k = 0; k < 8; ++k) {
        int e = base + k * 256 + tid;
        if (e < NE) {
            int d = dst[e];
            d_[k] = d;
            b_[k] = d >> 10;
            atomicAdd(&lcnt[b_[k]], 1);
        } else b_[k] = -1;
    }
    __syncthreads();
    if (tid < NBUCK) {
        lbase[tid] = (lcnt[tid] > 0) ? atomicAdd(&bcur[tid], lcnt[tid]) : 0;
        lcnt[tid] = 0;
    }
    __syncthreads();
    #pragma unroll
    for (int k = 0; k < 8; ++k) {
        int e = base + k * 256 + tid;
        if (e < NE) {
            int b = b_[k];
            int off = lbase[b] + atomicAdd(&lcnt[b], 1);
            const float* ea = edge_attr + (size_t)e * EF;
            uint4 pk;
            pk.x = (unsigned)src[e];
            pk.y = pkh2(ea[0], ea[1]);
            pk.z = pkh2(ea[2], ea[3]);
            pk.w = (unsigned)f2h_bits(ea[4]) | ((unsigned)d_[k] << 16);
            grouped[off] = pk;
        }
    }
}

__global__ void k_place(const uint4* __restrict__ grouped,
                        const int* __restrict__ row_start, int* __restrict__ cursor,
                        uint4* __restrict__ sorted_pk) {
    int e = blockIdx.x * blockDim.x + threadIdx.x;
    if (e >= NE) return;
    uint4 pk = grouped[e];
    int d = (int)(pk.w >> 16);
    int pos = atomicAdd(&cursor[d], 1);
    sorted_pk[row_start[d] + pos] = pk;
}

// ---------------------------------------------------------------------------
// k_esum (once): per node, sum incoming edge attrs -> attsum[v][8] =
// {a0..a4, deg, 0, 0}; emit compact sorted_srcc[e] (sequential write).
// ---------------------------------------------------------------------------
__global__ void k_esum(const uint4* __restrict__ sorted_pk,
                       const int* __restrict__ row_start,
                       float* __restrict__ attsum, int* __restrict__ sorted_srcc) {
    int v = blockIdx.x * blockDim.x + threadIdx.x;
    if (v >= NN) return;
    int e0 = row_start[v], e1 = row_start[v + 1];
    float s0 = 0.f, s1 = 0.f, s2 = 0.f, s3 = 0.f, s4 = 0.f;
    for (int e = e0; e < e1; ++e) {
        uint4 pk = sorted_pk[e];
        sorted_srcc[e] = (int)pk.x;
        float2 a01 = uph2(pk.y), a23 = uph2(pk.z);
        s0 += a01.x; s1 += a01.y; s2 += a23.x; s3 += a23.y;
        s4 += h_bits2f((unsigned short)(pk.w & 0xffffu));
    }
    float* o = attsum + (size_t)v * 8;
    *(float4*)(o) = make_float4(s0, s1, s2, s3);
    *(float4*)(o + 4) = make_float4(s4, (float)(e1 - e0), 0.f, 0.f);
}

// ---------------------------------------------------------------------------
// k_agg: agg[v] = h[v] + (deg+1)*bs + attsum[v]@W_e + sum_e h[src].
// One wave per node, 2 cols/lane, readfirstlane'd SGPR-base gathers.
// MAIN LOOP NOW 16-DEEP: all 16 gathers issued before accumulation (two
// independent 8-trees, fp32-flushed separately -> identical numerics).
// Avg-degree-16 nodes run ONE 16-deep batch instead of two dependent 8-deep
// rounds — halves the serial latency chain. Blocks 0..31 zero BN-stats.
// ---------------------------------------------------------------------------
__global__ __launch_bounds__(256) void k_agg(
        const unsigned short* __restrict__ h16, const int* __restrict__ sorted_srcc,
        const float* __restrict__ attsum,
        const float* __restrict__ W_e_l, const float* __restrict__ bsum_e_l,
        const int* __restrict__ row_start,
        unsigned short* __restrict__ agg16, float* __restrict__ stats) {
    int tid = threadIdx.x;
    if (blockIdx.x < NREP) stats[blockIdx.x * 2 * EMB + tid] = 0.f;  // 256 == 2*EMB
    int gid = blockIdx.x * 256 + tid;
    int v = gid >> 6;
    if (v >= NN) return;
    int c = (gid & 63) << 1;
    float2 we0 = *(const float2*)(W_e_l + 0 * EMB + c);
    float2 we1 = *(const float2*)(W_e_l + 1 * EMB + c);
    float2 we2 = *(const float2*)(W_e_l + 2 * EMB + c);
    float2 we3 = *(const float2*)(W_e_l + 3 * EMB + c);
    float2 we4 = *(const float2*)(W_e_l + 4 * EMB + c);
    float2 bs = *(const float2*)(bsum_e_l + c);
    float2 hv = uph2(*(const unsigned*)(h16 + (size_t)v * EMB + c));
    const float* at = attsum + (size_t)v * 8;
    float4 a03 = *(const float4*)(at);
    float2 a45 = *(const float2*)(at + 4);   // a4, deg
    float ax = hv.x + (a45.y + 1.f) * bs.x
             + a03.x*we0.x + a03.y*we1.x + a03.z*we2.x + a03.w*we3.x + a45.x*we4.x;
    float ay = hv.y + (a45.y + 1.f) * bs.y
             + a03.x*we0.y + a03.y*we1.y + a03.z*we2.y + a03.w*we3.y + a45.x*we4.y;
    int e0 = row_start[v], e1 = row_start[v + 1];
    int e = e0;
    for (; e + 16 <= e1; e += 16) {
        int s0 = __builtin_amdgcn_readfirstlane(sorted_srcc[e + 0]);
        int s1 = __builtin_amdgcn_readfirstlane(sorted_srcc[e + 1]);
        int s2 = __builtin_amdgcn_readfirstlane(sorted_srcc[e + 2]);
        int s3 = __builtin_amdgcn_readfirstlane(sorted_srcc[e + 3]);
        int s4 = __builtin_amdgcn_readfirstlane(sorted_srcc[e + 4]);
        int s5 = __builtin_amdgcn_readfirstlane(sorted_srcc[e + 5]);
        int s6 = __builtin_amdgcn_readfirstlane(sorted_srcc[e + 6]);
        int s7 = __builtin_amdgcn_readfirstlane(sorted_srcc[e + 7]);
        int s8 = __builtin_amdgcn_readfirstlane(sorted_srcc[e + 8]);
        int s9 = __builtin_amdgcn_readfirstlane(sorted_srcc[e + 9]);
        int sa = __builtin_amdgcn_readfirstlane(sorted_srcc[e + 10]);
        int sb = __builtin_amdgcn_readfirstlane(sorted_srcc[e + 11]);
        int sc = __builtin_amdgcn_readfirstlane(sorted_srcc[e + 12]);
        int sd = __builtin_amdgcn_readfirstlane(sorted_srcc[e + 13]);
        int se = __builtin_amdgcn_readfirstlane(sorted_srcc[e + 14]);
        int sf = __builtin_amdgcn_readfirstlane(sorted_srcc[e + 15]);
        unsigned u0 = *(const unsigned*)(h16 + (size_t)s0 * EMB + c);
        unsigned u1 = *(const unsigned*)(h16 + (size_t)s1 * EMB + c);
        unsigned u2 = *(const unsigned*)(h16 + (size_t)s2 * EMB + c);
        unsigned u3 = *(const unsigned*)(h16 + (size_t)s3 * EMB + c);
        unsigned u4 = *(const unsigned*)(h16 + (size_t)s4 * EMB + c);
        unsigned u5 = *(const unsigned*)(h16 + (size_t)s5 * EMB + c);
        unsigned u6 = *(const unsigned*)(h16 + (size_t)s6 * EMB + c);
        unsigned u7 = *(const unsigned*)(h16 + (size_t)s7 * EMB + c);
        unsigned u8 = *(const unsigned*)(h16 + (size_t)s8 * EMB + c);
        unsigned u9 = *(const unsigned*)(h16 + (size_t)s9 * EMB + c);
        unsigned ua = *(const unsigned*)(h16 + (size_t)sa * EMB + c);
        unsigned ub = *(const unsigned*)(h16 + (size_t)sb * EMB + c);
        unsigned uc = *(const unsigned*)(h16 + (size_t)sc * EMB + c);
        unsigned ud = *(const unsigned*)(h16 + (size_t)sd * EMB + c);
        unsigned ue = *(const unsigned*)(h16 + (size_t)se * EMB + c);
        unsigned uf = *(const unsigned*)(h16 + (size_t)sf * EMB + c);
        f16x2 pA = ((as_h2(u0) + as_h2(u1)) + (as_h2(u2) + as_h2(u3)))
                 + ((as_h2(u4) + as_h2(u5)) + (as_h2(u6) + as_h2(u7)));
        f16x2 pB = ((as_h2(u8) + as_h2(u9)) + (as_h2(ua) + as_h2(ub)))
                 + ((as_h2(uc) + as_h2(ud)) + (as_h2(ue) + as_h2(uf)));
        ax += (float)pA.x + (float)pB.x;
        ay += (float)pA.y + (float)pB.y;
    }
    for (; e + 8 <= e1; e += 8) {
        int s0 = __builtin_amdgcn_readfirstlane(sorted_srcc[e + 0]);
        int s1 = __builtin_amdgcn_readfirstlane(sorted_srcc[e + 1]);
        int s2 = __builtin_amdgcn_readfirstlane(sorted_srcc[e + 2]);
        int s3 = __builtin_amdgcn_readfirstlane(sorted_srcc[e + 3]);
        int s4 = __builtin_amdgcn_readfirstlane(sorted_srcc[e + 4]);
        int s5 = __builtin_amdgcn_readfirstlane(sorted_srcc[e + 5]);
        int s6 = __builtin_amdgcn_readfirstlane(sorted_srcc[e + 6]);
        int s7 = __builtin_amdgcn_readfirstlane(sorted_srcc[e + 7]);
        unsigned u0 = *(const unsigned*)(h16 + (size_t)s0 * EMB + c);
        unsigned u1 = *(const unsigned*)(h16 + (size_t)s1 * EMB + c);
        unsigned u2 = *(const unsigned*)(h16 + (size_t)s2 * EMB + c);
        unsigned u3 = *(const unsigned*)(h16 + (size_t)s3 * EMB + c);
        unsigned u4 = *(const unsigned*)(h16 + (size_t)s4 * EMB + c);
        unsigned u5 = *(const unsigned*)(h16 + (size_t)s5 * EMB + c);
        unsigned u6 = *(const unsigned*)(h16 + (size_t)s6 * EMB + c);
        unsigned u7 = *(const unsigned*)(h16 + (size_t)s7 * EMB + c);
        f16x2 p07 = ((as_h2(u0) + as_h2(u1)) + (as_h2(u2) + as_h2(u3)))
                  + ((as_h2(u4) + as_h2(u5)) + (as_h2(u6) + as_h2(u7)));
        ax += (float)p07.x;
        ay += (float)p07.y;
    }
    for (; e < e1; ++e) {
        int s = __builtin_amdgcn_readfirstlane(sorted_srcc[e]);
        float2 hs = uph2(*(const unsigned*)(h16 + (size_t)s * EMB + c));
        ax += hs.x;
        ay += hs.y;
    }
    *(unsigned*)(agg16 + (size_t)v * EMB + c) = pkh2(ax, ay);
}

// ---------------------------------------------------------------------------
// k_mlp (f16 MFMA), 64-row tile: activations single fp16 plane, weights
// fp16 hi/lo (2-term MFMA). LDS 51 KB -> 3 blocks/CU.
// D-frag: col=lane&15 (node), row=quad*4+reg. Writes z fp16; BN stats ->
// replicated buffers (blockIdx&31).
// ---------------------------------------------------------------------------
__global__ __launch_bounds__(256) void k_mlp(
        const unsigned short* __restrict__ agg16,
        const unsigned short* __restrict__ W1ph, const unsigned short* __restrict__ W1pl,
        const float* __restrict__ b1_l,
        const unsigned short* __restrict__ W2ph, const unsigned short* __restrict__ W2pl,
        const float* __restrict__ b2_l,
        unsigned short* __restrict__ z16, float* __restrict__ stats) {
    __shared__ unsigned short A16[64][136];    // 17 KB  (+8 pad)
    __shared__ unsigned short Hid16[64][264];  // 33.8 KB (+8 pad)
    int tid = threadIdx.x;
    int r0 = blockIdx.x * 64;
    int rep = blockIdx.x & (NREP - 1);
    // stage A tile (zero-pad rows >= NN): 1024 lane-16B loads = 4 iterations
    #pragma unroll
    for (int it = 0; it < 4; ++it) {
        int idx = it * 256 + tid;       // 0..1023
        int row = idx >> 4;
        int cb = (idx & 15) * 8;
        int grow = r0 + row;
        uint4 val = make_uint4(0u, 0u, 0u, 0u);
        if (grow < NN) val = *(const uint4*)(agg16 + (size_t)grow * EMB + cb);
        *(uint4*)(&A16[row][cb]) = val;
    }
    __syncthreads();
    int wave = tid >> 6, lane = tid & 63;
    int l16 = lane & 15, quad = lane >> 4;
    // ---- phase 1: wave owns hid cols [64*wave, 64*wave+64), all 64 rows
    {
        f16x8 af[4][4];
        #pragma unroll
        for (int nt = 0; nt < 4; ++nt)
            #pragma unroll
            for (int kk = 0; kk < 4; ++kk)
                af[nt][kk] = *(const f16x8*)(&A16[nt * 16 + l16][kk * 32 + quad * 8]);
        #pragma unroll
        for (int h2 = 0; h2 < 4; ++h2) {
            f16x8 whf[4], wlf[4];
            #pragma unroll
            for (int kk = 0; kk < 4; ++kk) {
                size_t off = ((((size_t)(wave * 4 + h2) * 4) + kk) * 64 + lane) * 8;
                whf[kk] = *(const f16x8*)(W1ph + off);
                wlf[kk] = *(const f16x8*)(W1pl + off);
            }
            float4 bv = *(const float4*)(b1_l + wave * 64 + h2 * 16 + quad * 4);
            f32x4 bias = {bv.x, bv.y, bv.z, bv.w};
            #pragma unroll
            for (int nt = 0; nt < 4; ++nt) {
                f32x4 acc = bias;
                #pragma unroll
                for (int kk = 0; kk < 4; ++kk)
                    acc = __builtin_amdgcn_mfma_f32_16x16x32_f16(whf[kk], af[nt][kk], acc, 0, 0, 0);
                #pragma unroll
                for (int kk = 0; kk < 4; ++kk)
                    acc = __builtin_amdgcn_mfma_f32_16x16x32_f16(wlf[kk], af[nt][kk], acc, 0, 0, 0);
                uint2 p;
                p.x = pkh2(fmaxf(acc[0], 0.f), fmaxf(acc[1], 0.f));
                p.y = pkh2(fmaxf(acc[2], 0.f), fmaxf(acc[3], 0.f));
                int col = wave * 64 + h2 * 16 + quad * 4;
                *(uint2*)(&Hid16[nt * 16 + l16][col]) = p;
            }
        }
    }
    __syncthreads();
    // ---- phase 2: wave owns out cols [32*wave, 32*wave+32), all 64 rows
    float ss[2][4] = {}, sq[2][4] = {};
    #pragma unroll
    for (int o2 = 0; o2 < 2; ++o2) {
        f16x8 w2h[8], w2l[8];
        #pragma unroll
        for (int kk = 0; kk < 8; ++kk) {
            size_t off = ((((size_t)(wave * 2 + o2) * 8) + kk) * 64 + lane) * 8;
            w2h[kk] = *(const f16x8*)(W2ph + off);
            w2l[kk] = *(const f16x8*)(W2pl + off);
        }
        float4 bv = *(const float4*)(b2_l + wave * 32 + o2 * 16 + quad * 4);
        f32x4 bias = {bv.x, bv.y, bv.z, bv.w};
        #pragma unroll
        for (int nt = 0; nt < 4; ++nt) {
            f16x8 hf[8];
            #pragma unroll
            for (int kk = 0; kk < 8; ++kk)
                hf[kk] = *(const f16x8*)(&Hid16[nt * 16 + l16][kk * 32 + quad * 8]);
            f32x4 acc = bias;
            #pragma unroll
            for (int kk = 0; kk < 8; ++kk)
                acc = __builtin_amdgcn_mfma_f32_16x16x32_f16(w2h[kk], hf[kk], acc, 0, 0, 0);
            #pragma unroll
            for (int kk = 0; kk < 8; ++kk)
                acc = __builtin_amdgcn_mfma_f32_16x16x32_f16(w2l[kk], hf[kk], acc, 0, 0, 0);
            int node = r0 + nt * 16 + l16;
            if (node < NN) {
                uint2 p = make_uint2(pkh2(acc[0], acc[1]), pkh2(acc[2], acc[3]));
                *(uint2*)(z16 + (size_t)node * EMB + wave * 32 + o2 * 16 + quad * 4) = p;
                #pragma unroll
                for (int r = 0; r < 4; ++r) {
                    ss[o2][r] += acc[r];
                    sq[o2][r] += acc[r] * acc[r];
                }
            }
        }
    }
    #pragma unroll
    for (int o2 = 0; o2 < 2; ++o2)
        #pragma unroll
        for (int r = 0; r < 4; ++r) {
            float s = ss[o2][r], q = sq[o2][r];
            #pragma unroll
            for (int m = 1; m < 16; m <<= 1) {
                s += __shfl_xor(s, m, 64);
                q += __shfl_xor(q, m, 64);
            }
            if (l16 == 0) {
                int oc = wave * 32 + o2 * 16 + quad * 4 + r;
                atomicAdd(&stats[rep * 2 * EMB + oc], s);
                atomicAdd(&stats[rep * 2 * EMB + EMB + oc], q);
            }
        }
}

// ---------------------------------------------------------------------------
// k_bnscale: ONE block reduces the NREP stats replicas -> sc/sh (1 KB).
// (Next layer's k_agg re-zeroes the replicas.)
// ---------------------------------------------------------------------------
__global__ void k_bnscale(const float* __restrict__ stats,
                          const float* __restrict__ gamma_l, const float* __restrict__ beta_l,
                          float* __restrict__ scsh) {
    int tid = threadIdx.x;  // 128 threads
    float s = 0.f, q = 0.f;
    #pragma unroll
    for (int r = 0; r < NREP; ++r) {
        s += stats[r * 2 * EMB + tid];
        q += stats[r * 2 * EMB + EMB + tid];
    }
    float mu = s * (1.f / NN);
    float var = q * (1.f / NN) - mu * mu;
    float sf = gamma_l[tid] * rsqrtf(var + BN_EPS);
    scsh[tid] = sf;
    scsh[EMB + tid] = beta_l[tid] - mu * sf;
}

// ---------------------------------------------------------------------------
// k_bn: z16 -> BN; ELU -> fp16 h (layers 0..3) or fp32 d_out (last layer).
// ---------------------------------------------------------------------------
__global__ void k_bn(const unsigned short* __restrict__ z16, const float* __restrict__ scsh,
                     unsigned short* __restrict__ h16, float* __restrict__ fout, int last) {
    __shared__ float sc[EMB], sh[EMB];
    int tid = threadIdx.x;
    if (tid < EMB) {
        sc[tid] = scsh[tid];
        sh[tid] = scsh[EMB + tid];
    }
    __syncthreads();
    int gid = blockIdx.x * blockDim.x + tid;
    if (gid >= NN * EMB / 4) return;
    int c = (gid & 31) << 2;
    uint2 zp = *(const uint2*)(z16 + (size_t)gid * 4);
    float2 z01 = uph2(zp.x), z23 = uph2(zp.y);
    float o0 = z01.x * sc[c + 0] + sh[c + 0];
    float o1 = z01.y * sc[c + 1] + sh[c + 1];
    float o2 = z23.x * sc[c + 2] + sh[c + 2];
    float o3 = z23.y * sc[c + 3] + sh[c + 3];
    if (!last) {
        o0 = (o0 > 0.f) ? o0 : (__expf(o0) - 1.f);
        o1 = (o1 > 0.f) ? o1 : (__expf(o1) - 1.f);
        o2 = (o2 > 0.f) ? o2 : (__expf(o2) - 1.f);
        o3 = (o3 > 0.f) ? o3 : (__expf(o3) - 1.f);
        uint2 p = make_uint2(pkh2(o0, o1), pkh2(o2, o3));
        *(uint2*)(h16 + (size_t)gid * 4) = p;
    } else {
        *(float4*)(fout + (size_t)gid * 4) = make_float4(o0, o1, o2, o3);
    }
}

// ---------------------------------------------------------------------------
extern "C" void kernel_launch(void* const* d_in, const int* in_sizes, int n_in,
                              void* d_out, int out_size, void* d_ws, size_t ws_size,
                              hipStream_t stream) {
    const float* x         = (const float*)d_in[0];
    const float* edge_attr = (const float*)d_in[1];
    const int*   edge_idx  = (const int*)d_in[2];
    const float* W_x   = (const float*)d_in[3];
    const float* b_x   = (const float*)d_in[4];
    const float* W_e   = (const float*)d_in[5];
    const float* b_e   = (const float*)d_in[6];
    const float* W1    = (const float*)d_in[7];
    const float* b1    = (const float*)d_in[8];
    const float* W2    = (const float*)d_in[9];
    const float* b2    = (const float*)d_in[10];
    const float* gamma = (const float*)d_in[11];
    const float* beta  = (const float*)d_in[12];
    float* fout = (float*)d_out;  // final BN writes fp32 here

    const int* src = edge_idx;
    const int* dst = edge_idx + NE;

    char* p = (char*)d_ws;
    auto alloc = [&](size_t bytes) { char* q = p; p += (bytes + 255) & ~(size_t)255; return q; };
    unsigned short* h16  = (unsigned short*)alloc((size_t)NN * EMB * 2);
    unsigned short* z16  = (unsigned short*)alloc((size_t)NN * EMB * 2);
    unsigned short* agg16 = (unsigned short*)alloc((size_t)NN * EMB * 2);
    unsigned short* W1ph = (unsigned short*)alloc((size_t)NL * HID * EMB * 2);
    unsigned short* W1pl = (unsigned short*)alloc((size_t)NL * HID * EMB * 2);
    unsigned short* W2ph = (unsigned short*)alloc((size_t)NL * EMB * HID * 2);
    unsigned short* W2pl = (unsigned short*)alloc((size_t)NL * EMB * HID * 2);
    int*   row_start  = (int*)alloc((NN + 1) * sizeof(int));
    int*   counts     = (int*)alloc(NN * sizeof(int));
    int*   cursor     = (int*)alloc(NN * sizeof(int));
    uint4* grouped    = (uint4*)alloc((size_t)NE * sizeof(uint4));
    uint4* sorted_pk  = (uint4*)alloc((size_t)NE * sizeof(uint4));
    int*   sorted_srcc= (int*)alloc((size_t)NE * sizeof(int));
    float* attsum     = (float*)alloc((size_t)NN * 8 * sizeof(float));
    int*   bsum       = (int*)alloc(SCAN_B * sizeof(int));
    int*   bpre       = (int*)alloc(SCAN_B * sizeof(int));
    int*   bcur       = (int*)alloc(NBUCK * sizeof(int));
    float* stats      = (float*)alloc((size_t)NREP * 2 * EMB * sizeof(float));
    float* scsh       = (float*)alloc(2 * EMB * sizeof(float));
    float* bsum_x     = (float*)alloc(EMB * sizeof(float));
    float* bsum_e     = (float*)alloc(NL * EMB * sizeof(float));

    k_prep<<<256, 256, 0, stream>>>(b_x, b_e, bsum_x, bsum_e, counts, cursor);
    k_prepw<<<(2 * NL * EMB * HID + 255) / 256, 256, 0, stream>>>(W1, W2, W1ph, W1pl, W2ph, W2pl);
    k_init<<<(NN * 32 + 255) / 256, 256, 0, stream>>>(x, W_x, bsum_x, h16);
    k_hist<<<(NE + 255) / 256, 256, 0, stream>>>(dst, counts);
    k_scan1<<<SCAN_B, 256, 0, stream>>>(counts, bsum);
    k_scan2<<<1, 256, 0, stream>>>(bsum, bpre, row_start);
    k_scan3<<<SCAN_B, 256, 0, stream>>>(counts, bpre, row_start, bcur);
    k_bucket<<<(NE + BPB - 1) / BPB, 256, 0, stream>>>(src, dst, edge_attr, bcur, grouped);
    k_place<<<(NE + 255) / 256, 256, 0, stream>>>(grouped, row_start, cursor, sorted_pk);
    k_esum<<<SCAN_B, 256, 0, stream>>>(sorted_pk, row_start, attsum, sorted_srcc);
    const int AGG_GRID = (NN * 64 + 255) / 256;
    for (int l = 0; l < NL; ++l) {
        k_agg<<<AGG_GRID, 256, 0, stream>>>(
            h16, sorted_srcc, attsum,
            W_e + (size_t)l * EF * EMB, bsum_e + l * EMB, row_start,
            agg16, stats);
        k_mlp<<<(NN + 63) / 64, 256, 0, stream>>>(
            agg16,
            W1ph + (size_t)l * HID * EMB, W1pl + (size_t)l * HID * EMB, b1 + (size_t)l * HID,
            W2ph + (size_t)l * EMB * HID, W2pl + (size_t)l * EMB * HID, b2 + (size_t)l * EMB,
            z16, stats);
        k_bnscale<<<1, 128, 0, stream>>>(stats, gamma + l * EMB, beta + l * EMB, scsh);
        k_bn<<<(NN * EMB / 4 + 255) / 256, 256, 0, stream>>>(
            z16, scsh, h16, fout, (l == NL - 1) ? 1 : 0);
    }
}